// Round 6
// baseline (478.530 us; speedup 1.0000x reference)
//
#include <hip/hip_runtime.h>

#define EPS 1e-5f

// ---- d_ws layout (float offsets unless noted) ----
#define W1OT 0          //   648  offset1_w [t*4+c][18] (c=3 zero-pad)
#define W1T  1024       //  2304  conv1_w   [t*4+c][64] (c=3 zero-pad)
#define W2T  4096       // 73728 ushorts: conv2_w bf16 [t][n=cout128][c64]
#define W2OB 40960      // 36864 ushorts: offset2_w split-bf16 BT [hl][n=32pad][k=576]
#define SC1  59392      //    64  bn1 scale
#define SH1  59456      //    64  bn1 shift (bias folded)
#define SC2  59520      //   128  bn2 scale
#define SH2  59648      //   128  bn2 shift (bias folded)
#define POOL 59776      //  4096  pooled sums (zeroed in prep)
#define XP   65536      // 524288  x as NHWC4 fp32 [b][hw][4] (ch3=0)
#define H1B  589824     // 8388608 ushorts: h1 bf16 NHWC [b][hw][64]
#define OFF2 4784128    // 2359296 pixel-major [b][hw][18]
// end 7143424 floats = 28.6 MiB
#define W2T_U   8192    // ushort offsets
#define W2OB_U  81920
#define H1B_U   1179648

typedef __attribute__((ext_vector_type(8))) short bhalf8;
typedef __attribute__((ext_vector_type(8))) unsigned short u16x8;
typedef __attribute__((ext_vector_type(4))) float f32x4;

#define BPAD 72   // LDS k-stride (ushorts): 144B -> 2-way (free) on frag reads

struct Tap { int i00, i01, i10, i11; float w00, w01, w10, w11; };

__device__ __forceinline__ Tap make_tap(float py, float px) {
    float y0f = floorf(py), x0f = floorf(px);
    float wy = py - y0f, wx = px - x0f;
    bool by0 = (y0f >= 0.f)  && (y0f < 64.f);
    bool by1 = (y0f >= -1.f) && (y0f < 63.f);
    bool bx0 = (x0f >= 0.f)  && (x0f < 64.f);
    bool bx1 = (x0f >= -1.f) && (x0f < 63.f);
    int y0 = min(max((int)y0f, 0), 63);
    int y1 = min(max((int)y0f + 1, 0), 63);
    int x0 = min(max((int)x0f, 0), 63);
    int x1 = min(max((int)x0f + 1, 0), 63);
    Tap tp;
    tp.i00 = y0 * 64 + x0; tp.i01 = y0 * 64 + x1;
    tp.i10 = y1 * 64 + x0; tp.i11 = y1 * 64 + x1;
    tp.w00 = (by0 && bx0) ? (1.f - wy) * (1.f - wx) : 0.f;
    tp.w01 = (by0 && bx1) ? (1.f - wy) * wx         : 0.f;
    tp.w10 = (by1 && bx0) ? wy * (1.f - wx)         : 0.f;
    tp.w11 = (by1 && bx1) ? wy * wx                 : 0.f;
    return tp;
}

__device__ __forceinline__ ushort f2bf(float f) {
    union { float f; uint u; } a; a.f = f;
    uint u = a.u;
    return (ushort)((u + 0x7fffu + ((u >> 16) & 1u)) >> 16);   // RNE
}
__device__ __forceinline__ float bf2f(ushort u) {
    union { uint u; float f; } a; a.u = ((uint)u) << 16;
    return a.f;
}

// ---- prep: weight transposes + BN folding + pool zero + x NHWC4 pack ----
__global__ __launch_bounds__(256) void k_prep(
    const float* __restrict__ x,
    const float* __restrict__ o1w, const float* __restrict__ c1w,
    const float* __restrict__ o2w, const float* __restrict__ c2w,
    const float* __restrict__ c1b, const float* __restrict__ g1,
    const float* __restrict__ be1, const float* __restrict__ m1,
    const float* __restrict__ v1,
    const float* __restrict__ c2b, const float* __restrict__ g2,
    const float* __restrict__ be2, const float* __restrict__ m2,
    const float* __restrict__ v2,
    float* __restrict__ ws) {
    int tid = blockIdx.x * 256 + threadIdx.x;
    ushort* wsu = (ushort*)ws;
    if (tid < 648) {                          // W1OT [t*4+c][18]
        int co = tid % 18, tc = tid / 18, c = tc & 3, t = tc >> 2;
        ws[W1OT + tid] = (c < 3) ? o1w[(co * 3 + c) * 9 + t] : 0.f;
    } else if (tid < 2952) {                  // W1T [t*4+c][64]
        int i = tid - 648;
        int co = i & 63, tc = i >> 6, c = tc & 3, t = tc >> 2;
        ws[W1T + i] = (c < 3) ? c1w[(co * 3 + c) * 9 + t] : 0.f;
    } else if (tid < 76680) {                 // W2T bf16 [t][n][c]
        int i = tid - 2952;
        int c = i & 63, n = (i >> 6) & 127, t = i >> 13;
        wsu[W2T_U + i] = f2bf(c2w[(n * 64 + c) * 9 + t]);
    } else if (tid < 113544) {                // W2OB split-bf16 BT [hl][n][k]
        int i = tid - 76680;
        int hl = i / 18432, rem = i - hl * 18432;
        int n = rem / 576, k = rem - n * 576;
        int c = k & 63, t = k >> 6;
        float v = (n < 18) ? o2w[(n * 64 + c) * 9 + t] : 0.f;
        ushort hi = f2bf(v);
        wsu[W2OB_U + i] = hl ? f2bf(v - bf2f(hi)) : hi;
    } else if (tid < 113608) {
        int i = tid - 113544;
        float s = g1[i] * rsqrtf(v1[i] + EPS);
        ws[SC1 + i] = s;
        ws[SH1 + i] = (c1b[i] - m1[i]) * s + be1[i];
    } else if (tid < 113736) {
        int i = tid - 113608;
        float s = g2[i] * rsqrtf(v2[i] + EPS);
        ws[SC2 + i] = s;
        ws[SH2 + i] = (c2b[i] - m2[i]) * s + be2[i];
    } else if (tid < 117832) {
        ws[POOL + tid - 113736] = 0.f;
    } else if (tid < 248904) {                // XP pack: x NCHW -> NHWC4
        int i = tid - 117832;                 // = b*4096 + hw
        int b = i >> 12, hw = i & 4095;
        const float* xpp = x + (size_t)b * 3 * 4096 + hw;
        f32x4 o;
        o[0] = xpp[0]; o[1] = xpp[4096]; o[2] = xpp[8192]; o[3] = 0.f;
        *(f32x4*)(ws + XP + (size_t)i * 4) = o;
    }
}

// ---- fused offset-conv1 + deform conv1 (3->64) + BN + ReLU -> h1 bf16 NHWC ----
// 2 threads per pixel (part = tid&1 handles 32 cout each) for TLP; weights in LDS.
__global__ __launch_bounds__(256, 4) void k_def1(
    const float* __restrict__ o1b, float* __restrict__ ws) {
    __shared__ float wo[648];
    __shared__ float wt[2304];
    for (int i = threadIdx.x; i < 648; i += 256) wo[i] = ws[W1OT + i];
    for (int i = threadIdx.x; i < 2304; i += 256) wt[i] = ws[W1T + i];
    __syncthreads();
    int gtid = blockIdx.x * 256 + threadIdx.x;
    int pix = gtid >> 1, part = gtid & 1;
    int b = pix >> 12, hw = pix & 4095, h = hw >> 6, w = hw & 63;
    const float* xp = ws + XP + (size_t)b * 16384;   // [hw][4]
    // off1 conv in registers (duplicated across the pair -- cheap VALU)
    float off[18];
#pragma unroll
    for (int i = 0; i < 18; ++i) off[i] = o1b[i];
#pragma unroll
    for (int t = 0; t < 9; ++t) {
        int yy = h + t / 3 - 1, xx = w + t % 3 - 1;
        f32x4 pv = (f32x4)0.f;
        if (yy >= 0 && yy < 64 && xx >= 0 && xx < 64)
            pv = *(const f32x4*)(xp + (yy * 64 + xx) * 4);
#pragma unroll
        for (int c = 0; c < 3; ++c) {
            const float* wp = wo + (t * 4 + c) * 18;
#pragma unroll
            for (int co = 0; co < 18; ++co) off[co] += pv[c] * wp[co];
        }
    }
    // deformed bilinear gather (4-ch vector taps)
    f32x4 v[9];
#pragma unroll
    for (int t = 0; t < 9; ++t) {
        Tap tp = make_tap((float)(h + t / 3 - 1) + off[2 * t],
                          (float)(w + t % 3 - 1) + off[2 * t + 1]);
        f32x4 c00 = *(const f32x4*)(xp + tp.i00 * 4);
        f32x4 c01 = *(const f32x4*)(xp + tp.i01 * 4);
        f32x4 c10 = *(const f32x4*)(xp + tp.i10 * 4);
        f32x4 c11 = *(const f32x4*)(xp + tp.i11 * 4);
        v[t] = tp.w00 * c00 + tp.w01 * c01 + tp.w10 * c10 + tp.w11 * c11;
    }
    // this thread's 32 output channels
    float acc[32];
#pragma unroll
    for (int i = 0; i < 32; ++i) acc[i] = 0.f;
#pragma unroll
    for (int t = 0; t < 9; ++t)
#pragma unroll
        for (int c = 0; c < 3; ++c) {
            float vk = v[t][c];
            const float* wp = wt + (t * 4 + c) * 64 + part * 32;
#pragma unroll
            for (int co = 0; co < 32; ++co) acc[co] += vk * wp[co];
        }
    const float* sc = ws + SC1 + part * 32;
    const float* sh = ws + SH1 + part * 32;
    ushort ob[32];
#pragma unroll
    for (int i = 0; i < 32; ++i)
        ob[i] = f2bf(fmaxf(acc[i] * sc[i] + sh[i], 0.f));
    ushort* op = (ushort*)ws + H1B_U + (size_t)pix * 64 + part * 32;
#pragma unroll
    for (int i = 0; i < 4; ++i)
        *(uint4*)(op + i * 8) = *(const uint4*)(ob + i * 8);
}

// ---- offset conv2 as bf16 MFMA GEMM (hi/lo split weights) -> off2 [b][hw][18] ----
// M=131072 px, K=576, N=32 (18 padded). WG=256 covers 1 row (M=64); wave M=16.
__global__ __launch_bounds__(256, 4) void k_off2(
    const float* __restrict__ o2b, float* __restrict__ ws) {
    int g = blockIdx.x;
    int b = (g & 7) * 4 + ((g >> 3) & 3);    // 4 images per XCD
    int row = g >> 5;
    int tid = threadIdx.x, lane = tid & 63, wv = tid >> 6;
    int r = lane & 15, q = lane >> 4;
    int hw0 = row * 64 + wv * 16;
    const ushort* hb = (const ushort*)ws + H1B_U + (size_t)b * 262144;
    const ushort* bt = (const ushort*)ws + W2OB_U;
    f32x4 acc[2];
    acc[0] = (f32x4)0.f; acc[1] = (f32x4)0.f;
#pragma unroll
    for (int t = 0; t < 9; ++t) {
        int yy = row + t / 3 - 1;
        int xx = wv * 16 + r + t % 3 - 1;
        bool val = (yy >= 0 && yy < 64 && xx >= 0 && xx < 64);
        int yyc = min(max(yy, 0), 63), xxc = min(max(xx, 0), 63);
        const ushort* ap = hb + (size_t)(yyc * 64 + xxc) * 64 + q * 8;
#pragma unroll
        for (int ks = 0; ks < 2; ++ks) {
            bhalf8 af = val ? *(const bhalf8*)(ap + ks * 32) : (bhalf8)(short)0;
            int kk = t * 64 + ks * 32 + q * 8;
#pragma unroll
            for (int nt = 0; nt < 2; ++nt) {
                bhalf8 bhi = *(const bhalf8*)(bt + (size_t)(nt * 16 + r) * 576 + kk);
                bhalf8 blo = *(const bhalf8*)(bt + 18432 + (size_t)(nt * 16 + r) * 576 + kk);
                acc[nt] = __builtin_amdgcn_mfma_f32_16x16x32_bf16(af, bhi, acc[nt], 0, 0, 0);
                acc[nt] = __builtin_amdgcn_mfma_f32_16x16x32_bf16(af, blo, acc[nt], 0, 0, 0);
            }
        }
    }
#pragma unroll
    for (int nt = 0; nt < 2; ++nt) {
        int n = nt * 16 + r;
        if (n < 18) {
            float bias = o2b[n];
#pragma unroll
            for (int rr = 0; rr < 4; ++rr) {
                int hw = hw0 + q * 4 + rr;
                ws[OFF2 + (size_t)(b * 4096 + hw) * 18 + n] = acc[nt][rr] + bias;
            }
        }
    }
}

// ---- deform conv2 (64->128) implicit-GEMM bf16 MFMA + BN + ReLU + pool ----
// Double-buffered LDS B (1 barrier/tap), offsets preloaded, full tap unroll.
__global__ __launch_bounds__(256, 3) void k_def2(float* __restrict__ ws) {
    __shared__ ushort Blds[2][128 * BPAD];
    int g = blockIdx.x;
    int b = (g & 7) * 4 + ((g >> 3) & 3);
    int row = g >> 5;
    int tid = threadIdx.x, lane = tid & 63, wv = tid >> 6;
    int r = lane & 15, q = lane >> 4;
    int px = wv * 16 + r;
    const ushort* hb = (const ushort*)ws + H1B_U + (size_t)b * 262144;
    const float* o2 = ws + OFF2 + (size_t)b * 73728 + (size_t)(row * 64 + px) * 18;
    const ushort* wB = (const ushort*)ws + W2T_U;
    int bn = tid >> 1, bc = (tid & 1) * 32;

    // preload all 9 taps' offsets (independent dwordx2 loads, issued up front)
    float2 off[9];
#pragma unroll
    for (int t = 0; t < 9; ++t) off[t] = *(const float2*)(o2 + 2 * t);

    // stage tap 0's B
    {
        const uint4* s4 = (const uint4*)(wB + bn * 64 + bc);
        uint4 p0 = s4[0], p1 = s4[1], p2 = s4[2], p3 = s4[3];
        ushort* dst = Blds[0] + bn * BPAD + bc;
        *(uint4*)(dst)      = p0;
        *(uint4*)(dst + 8)  = p1;
        *(uint4*)(dst + 16) = p2;
        *(uint4*)(dst + 24) = p3;
    }
    __syncthreads();

    f32x4 acc[8];
#pragma unroll
    for (int j = 0; j < 8; ++j) acc[j] = (f32x4)0.f;

#pragma unroll
    for (int t = 0; t < 9; ++t) {
        // issue next tap's B prefetch (lands in LDS at loop bottom)
        uint4 p0, p1, p2, p3;
        if (t < 8) {
            const uint4* s4 = (const uint4*)(wB + ((t + 1) * 128 + bn) * 64 + bc);
            p0 = s4[0]; p1 = s4[1]; p2 = s4[2]; p3 = s4[3];
        }
        Tap tp = make_tap((float)(row + t / 3 - 1) + off[t].x,
                          (float)(px + t % 3 - 1) + off[t].y);
        const ushort* Bcur = Blds[t & 1];
#pragma unroll
        for (int ks = 0; ks < 2; ++ks) {
            int ko = ks * 32 + q * 8;       // this lane's 8 channels
            bhalf8 bf[8];
#pragma unroll
            for (int nt = 0; nt < 8; ++nt)
                bf[nt] = *(const bhalf8*)(Bcur + (nt * 16 + r) * BPAD + ko);
            u16x8 g00 = *(const u16x8*)(hb + (size_t)tp.i00 * 64 + ko);
            u16x8 g01 = *(const u16x8*)(hb + (size_t)tp.i01 * 64 + ko);
            u16x8 g10 = *(const u16x8*)(hb + (size_t)tp.i10 * 64 + ko);
            u16x8 g11 = *(const u16x8*)(hb + (size_t)tp.i11 * 64 + ko);
            f32x4 lo = (f32x4)0.f, hi = (f32x4)0.f;
#pragma unroll
            for (int j = 0; j < 4; ++j) {
                lo[j] = tp.w00 * bf2f(g00[j]) + tp.w01 * bf2f(g01[j])
                      + tp.w10 * bf2f(g10[j]) + tp.w11 * bf2f(g11[j]);
                hi[j] = tp.w00 * bf2f(g00[j + 4]) + tp.w01 * bf2f(g01[j + 4])
                      + tp.w10 * bf2f(g10[j + 4]) + tp.w11 * bf2f(g11[j + 4]);
            }
            bhalf8 af;
#pragma unroll
            for (int j = 0; j < 4; ++j) {
                af[j]     = (short)f2bf(lo[j]);
                af[j + 4] = (short)f2bf(hi[j]);
            }
#pragma unroll
            for (int nt = 0; nt < 8; ++nt)
                acc[nt] = __builtin_amdgcn_mfma_f32_16x16x32_bf16(af, bf[nt], acc[nt], 0, 0, 0);
        }
        if (t < 8) {                        // store prefetch into the other buffer
            ushort* dst = Blds[(t + 1) & 1] + bn * BPAD + bc;
            *(uint4*)(dst)      = p0;
            *(uint4*)(dst + 8)  = p1;
            *(uint4*)(dst + 16) = p2;
            *(uint4*)(dst + 24) = p3;
            __syncthreads();                // one barrier per tap
        }
    }
    // epilogue: BN + ReLU + pool (h2 never materialized)
    const float* sc = ws + SC2;
    const float* sh = ws + SH2;
    float* pool = ws + POOL;
#pragma unroll
    for (int nt = 0; nt < 8; ++nt) {
        int col = nt * 16 + r;
        float s0 = sc[col], s1 = sh[col];
        float s = 0.f;
#pragma unroll
        for (int rr = 0; rr < 4; ++rr)
            s += fmaxf(acc[nt][rr] * s0 + s1, 0.f);
        s += __shfl_xor(s, 16);
        s += __shfl_xor(s, 32);
        if (lane < 16) atomicAdd(&pool[b * 128 + col], s);
    }
}

// ---- fused fc1+relu+fc2 ----
__global__ __launch_bounds__(256) void k_fc(
    const float* __restrict__ w1, const float* __restrict__ b1,
    const float* __restrict__ w2, const float* __restrict__ b2,
    const float* __restrict__ ws, float* __restrict__ out) {
    int b = blockIdx.x, o = threadIdx.x;
    __shared__ float pl[128];
    __shared__ float hl[256];
    if (o < 128) pl[o] = ws[POOL + b * 128 + o] * (1.f / 4096.f);
    __syncthreads();
    float s = b1[o];
    const float* wp = w1 + o * 128;
#pragma unroll 8
    for (int c = 0; c < 128; ++c) s += pl[c] * wp[c];
    hl[o] = fmaxf(s, 0.f);
    __syncthreads();
    if (o < 200) {
        float s2 = b2[o];
        const float* wp2 = w2 + o * 256;
#pragma unroll 8
        for (int c = 0; c < 256; ++c) s2 += hl[c] * wp2[c];
        out[b * 200 + o] = s2;
    }
}

extern "C" void kernel_launch(void* const* d_in, const int* in_sizes, int n_in,
                              void* d_out, int out_size, void* d_ws, size_t ws_size,
                              hipStream_t stream) {
    const float* x   = (const float*)d_in[0];
    const float* o1w = (const float*)d_in[1];
    const float* o1b = (const float*)d_in[2];
    const float* c1w = (const float*)d_in[3];
    const float* c1b = (const float*)d_in[4];
    const float* g1  = (const float*)d_in[5];
    const float* be1 = (const float*)d_in[6];
    const float* m1  = (const float*)d_in[7];
    const float* v1  = (const float*)d_in[8];
    const float* o2w = (const float*)d_in[9];
    const float* o2b = (const float*)d_in[10];
    const float* c2w = (const float*)d_in[11];
    const float* c2b = (const float*)d_in[12];
    const float* g2  = (const float*)d_in[13];
    const float* be2 = (const float*)d_in[14];
    const float* m2  = (const float*)d_in[15];
    const float* v2  = (const float*)d_in[16];
    const float* f1w = (const float*)d_in[17];
    const float* f1b = (const float*)d_in[18];
    const float* f2w = (const float*)d_in[19];
    const float* f2b = (const float*)d_in[20];
    float* ws  = (float*)d_ws;
    float* out = (float*)d_out;

    k_prep<<<973, 256, 0, stream>>>(x, o1w, c1w, o2w, c2w,
                                    c1b, g1, be1, m1, v1,
                                    c2b, g2, be2, m2, v2, ws);
    k_def1<<<1024, 256, 0, stream>>>(o1b, ws);
    k_off2<<<2048, 256, 0, stream>>>(o2b, ws);
    k_def2<<<2048, 256, 0, stream>>>(ws);
    k_fc<<<32, 256, 0, stream>>>(f1w, f1b, f2w, f2b, ws, out);
}

// Round 7
// 373.089 us; speedup vs baseline: 1.2826x; 1.2826x over previous
//
#include <hip/hip_runtime.h>

#define EPS 1e-5f

// ---- d_ws layout (float offsets unless noted) ----
#define W1OT 0          //   648  offset1_w [t*4+c][18] (c=3 zero-pad)
#define W1T  1024       //  2304  conv1_w   [t*4+c][64] (c=3 zero-pad)
#define W2T  4096       // 73728 ushorts: conv2_w bf16 [t][n=cout128][c64]
#define W2OB 40960      // 36864 ushorts: offset2_w split-bf16 BT [hl][n=32pad][k=576]
#define SC1  59392      //    64  bn1 scale
#define SH1  59456      //    64  bn1 shift (bias folded)
#define SC2  59520      //   128  bn2 scale
#define SH2  59648      //   128  bn2 shift (bias folded)
#define POOL 59776      //  4096  pooled sums (zeroed in prep)
#define XP   65536      // 524288  x as NHWC4 fp32 [b][hw][4] (ch3=0)
#define H1B  589824     // 8388608 ushorts: h1 bf16 NHWC [b][hw][64]
#define OFF2 4784128    // 2359296 pixel-major [b][hw][18]
// end 7143424 floats = 28.6 MiB
#define W2T_U   8192    // ushort offsets
#define W2OB_U  81920
#define H1B_U   1179648

typedef __attribute__((ext_vector_type(8))) short bhalf8;
typedef __attribute__((ext_vector_type(8))) unsigned short u16x8;
typedef __attribute__((ext_vector_type(4))) float f32x4;

#define BPAD 72   // LDS k-stride (ushorts): 144B -> 2-way (free) on frag reads

struct Tap { int i00, i01, i10, i11; float w00, w01, w10, w11; };

__device__ __forceinline__ Tap make_tap(float py, float px) {
    float y0f = floorf(py), x0f = floorf(px);
    float wy = py - y0f, wx = px - x0f;
    bool by0 = (y0f >= 0.f)  && (y0f < 64.f);
    bool by1 = (y0f >= -1.f) && (y0f < 63.f);
    bool bx0 = (x0f >= 0.f)  && (x0f < 64.f);
    bool bx1 = (x0f >= -1.f) && (x0f < 63.f);
    int y0 = min(max((int)y0f, 0), 63);
    int y1 = min(max((int)y0f + 1, 0), 63);
    int x0 = min(max((int)x0f, 0), 63);
    int x1 = min(max((int)x0f + 1, 0), 63);
    Tap tp;
    tp.i00 = y0 * 64 + x0; tp.i01 = y0 * 64 + x1;
    tp.i10 = y1 * 64 + x0; tp.i11 = y1 * 64 + x1;
    tp.w00 = (by0 && bx0) ? (1.f - wy) * (1.f - wx) : 0.f;
    tp.w01 = (by0 && bx1) ? (1.f - wy) * wx         : 0.f;
    tp.w10 = (by1 && bx0) ? wy * (1.f - wx)         : 0.f;
    tp.w11 = (by1 && bx1) ? wy * wx                 : 0.f;
    return tp;
}

__device__ __forceinline__ ushort f2bf(float f) {
    union { float f; uint u; } a; a.f = f;
    uint u = a.u;
    return (ushort)((u + 0x7fffu + ((u >> 16) & 1u)) >> 16);   // RNE
}
__device__ __forceinline__ float bf2f(ushort u) {
    union { uint u; float f; } a; a.u = ((uint)u) << 16;
    return a.f;
}

// ---- prep: weight transposes + BN folding + pool zero + x NHWC4 pack ----
__global__ __launch_bounds__(256) void k_prep(
    const float* __restrict__ x,
    const float* __restrict__ o1w, const float* __restrict__ c1w,
    const float* __restrict__ o2w, const float* __restrict__ c2w,
    const float* __restrict__ c1b, const float* __restrict__ g1,
    const float* __restrict__ be1, const float* __restrict__ m1,
    const float* __restrict__ v1,
    const float* __restrict__ c2b, const float* __restrict__ g2,
    const float* __restrict__ be2, const float* __restrict__ m2,
    const float* __restrict__ v2,
    float* __restrict__ ws) {
    int tid = blockIdx.x * 256 + threadIdx.x;
    ushort* wsu = (ushort*)ws;
    if (tid < 648) {                          // W1OT [t*4+c][18]
        int co = tid % 18, tc = tid / 18, c = tc & 3, t = tc >> 2;
        ws[W1OT + tid] = (c < 3) ? o1w[(co * 3 + c) * 9 + t] : 0.f;
    } else if (tid < 2952) {                  // W1T [t*4+c][64]
        int i = tid - 648;
        int co = i & 63, tc = i >> 6, c = tc & 3, t = tc >> 2;
        ws[W1T + i] = (c < 3) ? c1w[(co * 3 + c) * 9 + t] : 0.f;
    } else if (tid < 76680) {                 // W2T bf16 [t][n][c]
        int i = tid - 2952;
        int c = i & 63, n = (i >> 6) & 127, t = i >> 13;
        wsu[W2T_U + i] = f2bf(c2w[(n * 64 + c) * 9 + t]);
    } else if (tid < 113544) {                // W2OB split-bf16 BT [hl][n][k]
        int i = tid - 76680;
        int hl = i / 18432, rem = i - hl * 18432;
        int n = rem / 576, k = rem - n * 576;
        int c = k & 63, t = k >> 6;
        float v = (n < 18) ? o2w[(n * 64 + c) * 9 + t] : 0.f;
        ushort hi = f2bf(v);
        wsu[W2OB_U + i] = hl ? f2bf(v - bf2f(hi)) : hi;
    } else if (tid < 113608) {
        int i = tid - 113544;
        float s = g1[i] * rsqrtf(v1[i] + EPS);
        ws[SC1 + i] = s;
        ws[SH1 + i] = (c1b[i] - m1[i]) * s + be1[i];
    } else if (tid < 113736) {
        int i = tid - 113608;
        float s = g2[i] * rsqrtf(v2[i] + EPS);
        ws[SC2 + i] = s;
        ws[SH2 + i] = (c2b[i] - m2[i]) * s + be2[i];
    } else if (tid < 117832) {
        ws[POOL + tid - 113736] = 0.f;
    } else if (tid < 248904) {                // XP pack: x NCHW -> NHWC4
        int i = tid - 117832;                 // = b*4096 + hw
        int b = i >> 12, hw = i & 4095;
        const float* xpp = x + (size_t)b * 3 * 4096 + hw;
        f32x4 o;
        o[0] = xpp[0]; o[1] = xpp[4096]; o[2] = xpp[8192]; o[3] = 0.f;
        *(f32x4*)(ws + XP + (size_t)i * 4) = o;
    }
}

// ---- fused offset-conv1 + deform conv1 (3->64) + BN + ReLU -> h1 bf16 NHWC ----
// Round-5 version (proven no-spill): 1 thread/pixel, LDS weights, 2x32 acc chunks.
__global__ __launch_bounds__(256, 4) void k_def1(
    const float* __restrict__ o1b, float* __restrict__ ws) {
    __shared__ float wo[648];
    __shared__ float wt[2304];
    for (int i = threadIdx.x; i < 648; i += 256) wo[i] = ws[W1OT + i];
    for (int i = threadIdx.x; i < 2304; i += 256) wt[i] = ws[W1T + i];
    __syncthreads();
    int tid = blockIdx.x * 256 + threadIdx.x;
    int b = tid >> 12, hw = tid & 4095, h = hw >> 6, w = hw & 63;
    const float* xp = ws + XP + (size_t)b * 16384;   // [hw][4]
    // off1 conv in registers
    float off[18];
#pragma unroll
    for (int i = 0; i < 18; ++i) off[i] = o1b[i];
#pragma unroll
    for (int t = 0; t < 9; ++t) {
        int yy = h + t / 3 - 1, xx = w + t % 3 - 1;
        f32x4 pv = (f32x4)0.f;
        if (yy >= 0 && yy < 64 && xx >= 0 && xx < 64)
            pv = *(const f32x4*)(xp + (yy * 64 + xx) * 4);
#pragma unroll
        for (int c = 0; c < 3; ++c) {
            const float* wp = wo + (t * 4 + c) * 18;
#pragma unroll
            for (int co = 0; co < 18; ++co) off[co] += pv[c] * wp[co];
        }
    }
    // deformed bilinear gather (4-ch vector taps)
    f32x4 v[9];
#pragma unroll
    for (int t = 0; t < 9; ++t) {
        Tap tp = make_tap((float)(h + t / 3 - 1) + off[2 * t],
                          (float)(w + t % 3 - 1) + off[2 * t + 1]);
        f32x4 c00 = *(const f32x4*)(xp + tp.i00 * 4);
        f32x4 c01 = *(const f32x4*)(xp + tp.i01 * 4);
        f32x4 c10 = *(const f32x4*)(xp + tp.i10 * 4);
        f32x4 c11 = *(const f32x4*)(xp + tp.i11 * 4);
        v[t] = tp.w00 * c00 + tp.w01 * c01 + tp.w10 * c10 + tp.w11 * c11;
    }
    const float* sc = ws + SC1;
    const float* sh = ws + SH1;
    ushort* op = (ushort*)ws + H1B_U + (size_t)(b * 4096 + hw) * 64;
#pragma unroll
    for (int ch = 0; ch < 2; ++ch) {
        float acc[32];
#pragma unroll
        for (int i = 0; i < 32; ++i) acc[i] = 0.f;
#pragma unroll
        for (int t = 0; t < 9; ++t)
#pragma unroll
            for (int c = 0; c < 3; ++c) {
                float vk = v[t][c];
                const float* wp = wt + (t * 4 + c) * 64 + ch * 32;
#pragma unroll
                for (int co = 0; co < 32; ++co) acc[co] += vk * wp[co];
            }
        ushort ob[32];
#pragma unroll
        for (int i = 0; i < 32; ++i) {
            int co = ch * 32 + i;
            ob[i] = f2bf(fmaxf(acc[i] * sc[co] + sh[co], 0.f));
        }
#pragma unroll
        for (int i = 0; i < 4; ++i)
            *(uint4*)(op + ch * 32 + i * 8) = *(const uint4*)(ob + i * 8);
    }
}

// ---- offset conv2 as bf16 MFMA GEMM (hi/lo split weights) -> off2 [b][hw][18] ----
// M=131072 px, K=576, N=32 (18 padded). WG=256 covers 1 row (M=64); wave M=16.
__global__ __launch_bounds__(256, 4) void k_off2(
    const float* __restrict__ o2b, float* __restrict__ ws) {
    int g = blockIdx.x;
    int b = (g & 7) * 4 + ((g >> 3) & 3);    // 4 images per XCD
    int row = g >> 5;
    int tid = threadIdx.x, lane = tid & 63, wv = tid >> 6;
    int r = lane & 15, q = lane >> 4;
    int hw0 = row * 64 + wv * 16;
    const ushort* hb = (const ushort*)ws + H1B_U + (size_t)b * 262144;
    const ushort* bt = (const ushort*)ws + W2OB_U;
    f32x4 acc[2];
    acc[0] = (f32x4)0.f; acc[1] = (f32x4)0.f;
#pragma unroll
    for (int t = 0; t < 9; ++t) {
        int yy = row + t / 3 - 1;
        int xx = wv * 16 + r + t % 3 - 1;
        bool val = (yy >= 0 && yy < 64 && xx >= 0 && xx < 64);
        int yyc = min(max(yy, 0), 63), xxc = min(max(xx, 0), 63);
        const ushort* ap = hb + (size_t)(yyc * 64 + xxc) * 64 + q * 8;
#pragma unroll
        for (int ks = 0; ks < 2; ++ks) {
            bhalf8 af = val ? *(const bhalf8*)(ap + ks * 32) : (bhalf8)(short)0;
            int kk = t * 64 + ks * 32 + q * 8;
#pragma unroll
            for (int nt = 0; nt < 2; ++nt) {
                bhalf8 bhi = *(const bhalf8*)(bt + (size_t)(nt * 16 + r) * 576 + kk);
                bhalf8 blo = *(const bhalf8*)(bt + 18432 + (size_t)(nt * 16 + r) * 576 + kk);
                acc[nt] = __builtin_amdgcn_mfma_f32_16x16x32_bf16(af, bhi, acc[nt], 0, 0, 0);
                acc[nt] = __builtin_amdgcn_mfma_f32_16x16x32_bf16(af, blo, acc[nt], 0, 0, 0);
            }
        }
    }
#pragma unroll
    for (int nt = 0; nt < 2; ++nt) {
        int n = nt * 16 + r;
        if (n < 18) {
            float bias = o2b[n];
#pragma unroll
            for (int rr = 0; rr < 4; ++rr) {
                int hw = hw0 + q * 4 + rr;
                ws[OFF2 + (size_t)(b * 4096 + hw) * 18 + n] = acc[nt][rr] + bias;
            }
        }
    }
}

// ---- deform conv2 (64->128) implicit-GEMM bf16 MFMA + BN + ReLU + pool ----
// Double-buffered LDS B (1 barrier/tap), offsets preloaded, full tap unroll.
__global__ __launch_bounds__(256, 3) void k_def2(float* __restrict__ ws) {
    __shared__ ushort Blds[2][128 * BPAD];
    int g = blockIdx.x;
    int b = (g & 7) * 4 + ((g >> 3) & 3);
    int row = g >> 5;
    int tid = threadIdx.x, lane = tid & 63, wv = tid >> 6;
    int r = lane & 15, q = lane >> 4;
    int px = wv * 16 + r;
    const ushort* hb = (const ushort*)ws + H1B_U + (size_t)b * 262144;
    const float* o2 = ws + OFF2 + (size_t)b * 73728 + (size_t)(row * 64 + px) * 18;
    const ushort* wB = (const ushort*)ws + W2T_U;
    int bn = tid >> 1, bc = (tid & 1) * 32;

    // preload all 9 taps' offsets (independent dwordx2 loads, issued up front)
    float2 off[9];
#pragma unroll
    for (int t = 0; t < 9; ++t) off[t] = *(const float2*)(o2 + 2 * t);

    // stage tap 0's B
    {
        const uint4* s4 = (const uint4*)(wB + bn * 64 + bc);
        uint4 p0 = s4[0], p1 = s4[1], p2 = s4[2], p3 = s4[3];
        ushort* dst = Blds[0] + bn * BPAD + bc;
        *(uint4*)(dst)      = p0;
        *(uint4*)(dst + 8)  = p1;
        *(uint4*)(dst + 16) = p2;
        *(uint4*)(dst + 24) = p3;
    }
    __syncthreads();

    f32x4 acc[8];
#pragma unroll
    for (int j = 0; j < 8; ++j) acc[j] = (f32x4)0.f;

#pragma unroll
    for (int t = 0; t < 9; ++t) {
        // issue next tap's B prefetch (lands in LDS at loop bottom)
        uint4 p0, p1, p2, p3;
        if (t < 8) {
            const uint4* s4 = (const uint4*)(wB + ((t + 1) * 128 + bn) * 64 + bc);
            p0 = s4[0]; p1 = s4[1]; p2 = s4[2]; p3 = s4[3];
        }
        Tap tp = make_tap((float)(row + t / 3 - 1) + off[t].x,
                          (float)(px + t % 3 - 1) + off[t].y);
        const ushort* Bcur = Blds[t & 1];
#pragma unroll
        for (int ks = 0; ks < 2; ++ks) {
            int ko = ks * 32 + q * 8;       // this lane's 8 channels
            bhalf8 bf[8];
#pragma unroll
            for (int nt = 0; nt < 8; ++nt)
                bf[nt] = *(const bhalf8*)(Bcur + (nt * 16 + r) * BPAD + ko);
            u16x8 g00 = *(const u16x8*)(hb + (size_t)tp.i00 * 64 + ko);
            u16x8 g01 = *(const u16x8*)(hb + (size_t)tp.i01 * 64 + ko);
            u16x8 g10 = *(const u16x8*)(hb + (size_t)tp.i10 * 64 + ko);
            u16x8 g11 = *(const u16x8*)(hb + (size_t)tp.i11 * 64 + ko);
            f32x4 lo = (f32x4)0.f, hi = (f32x4)0.f;
#pragma unroll
            for (int j = 0; j < 4; ++j) {
                lo[j] = tp.w00 * bf2f(g00[j]) + tp.w01 * bf2f(g01[j])
                      + tp.w10 * bf2f(g10[j]) + tp.w11 * bf2f(g11[j]);
                hi[j] = tp.w00 * bf2f(g00[j + 4]) + tp.w01 * bf2f(g01[j + 4])
                      + tp.w10 * bf2f(g10[j + 4]) + tp.w11 * bf2f(g11[j + 4]);
            }
            bhalf8 af;
#pragma unroll
            for (int j = 0; j < 4; ++j) {
                af[j]     = (short)f2bf(lo[j]);
                af[j + 4] = (short)f2bf(hi[j]);
            }
#pragma unroll
            for (int nt = 0; nt < 8; ++nt)
                acc[nt] = __builtin_amdgcn_mfma_f32_16x16x32_bf16(af, bf[nt], acc[nt], 0, 0, 0);
        }
        if (t < 8) {                        // store prefetch into the other buffer
            ushort* dst = Blds[(t + 1) & 1] + bn * BPAD + bc;
            *(uint4*)(dst)      = p0;
            *(uint4*)(dst + 8)  = p1;
            *(uint4*)(dst + 16) = p2;
            *(uint4*)(dst + 24) = p3;
            __syncthreads();                // one barrier per tap
        }
    }
    // epilogue: BN + ReLU + pool (h2 never materialized)
    const float* sc = ws + SC2;
    const float* sh = ws + SH2;
    float* pool = ws + POOL;
#pragma unroll
    for (int nt = 0; nt < 8; ++nt) {
        int col = nt * 16 + r;
        float s0 = sc[col], s1 = sh[col];
        float s = 0.f;
#pragma unroll
        for (int rr = 0; rr < 4; ++rr)
            s += fmaxf(acc[nt][rr] * s0 + s1, 0.f);
        s += __shfl_xor(s, 16);
        s += __shfl_xor(s, 32);
        if (lane < 16) atomicAdd(&pool[b * 128 + col], s);
    }
}

// ---- fused fc1+relu+fc2 ----
__global__ __launch_bounds__(256) void k_fc(
    const float* __restrict__ w1, const float* __restrict__ b1,
    const float* __restrict__ w2, const float* __restrict__ b2,
    const float* __restrict__ ws, float* __restrict__ out) {
    int b = blockIdx.x, o = threadIdx.x;
    __shared__ float pl[128];
    __shared__ float hl[256];
    if (o < 128) pl[o] = ws[POOL + b * 128 + o] * (1.f / 4096.f);
    __syncthreads();
    float s = b1[o];
    const float* wp = w1 + o * 128;
#pragma unroll 8
    for (int c = 0; c < 128; ++c) s += pl[c] * wp[c];
    hl[o] = fmaxf(s, 0.f);
    __syncthreads();
    if (o < 200) {
        float s2 = b2[o];
        const float* wp2 = w2 + o * 256;
#pragma unroll 8
        for (int c = 0; c < 256; ++c) s2 += hl[c] * wp2[c];
        out[b * 200 + o] = s2;
    }
}

extern "C" void kernel_launch(void* const* d_in, const int* in_sizes, int n_in,
                              void* d_out, int out_size, void* d_ws, size_t ws_size,
                              hipStream_t stream) {
    const float* x   = (const float*)d_in[0];
    const float* o1w = (const float*)d_in[1];
    const float* o1b = (const float*)d_in[2];
    const float* c1w = (const float*)d_in[3];
    const float* c1b = (const float*)d_in[4];
    const float* g1  = (const float*)d_in[5];
    const float* be1 = (const float*)d_in[6];
    const float* m1  = (const float*)d_in[7];
    const float* v1  = (const float*)d_in[8];
    const float* o2w = (const float*)d_in[9];
    const float* o2b = (const float*)d_in[10];
    const float* c2w = (const float*)d_in[11];
    const float* c2b = (const float*)d_in[12];
    const float* g2  = (const float*)d_in[13];
    const float* be2 = (const float*)d_in[14];
    const float* m2  = (const float*)d_in[15];
    const float* v2  = (const float*)d_in[16];
    const float* f1w = (const float*)d_in[17];
    const float* f1b = (const float*)d_in[18];
    const float* f2w = (const float*)d_in[19];
    const float* f2b = (const float*)d_in[20];
    float* ws  = (float*)d_ws;
    float* out = (float*)d_out;

    k_prep<<<973, 256, 0, stream>>>(x, o1w, c1w, o2w, c2w,
                                    c1b, g1, be1, m1, v1,
                                    c2b, g2, be2, m2, v2, ws);
    k_def1<<<512, 256, 0, stream>>>(o1b, ws);
    k_off2<<<2048, 256, 0, stream>>>(o2b, ws);
    k_def2<<<2048, 256, 0, stream>>>(ws);
    k_fc<<<32, 256, 0, stream>>>(f1w, f1b, f2w, f2b, ws, out);
}

// Round 8
// 319.741 us; speedup vs baseline: 1.4966x; 1.1668x over previous
//
#include <hip/hip_runtime.h>

#define EPS 1e-5f

// ---- d_ws layout (float offsets unless noted) ----
#define W1OT 0          //   648  offset1_w [t*4+c][18] (c=3 zero-pad)
#define W1T  1024       //  2304  conv1_w   [t*4+c][64] (c=3 zero-pad)
#define W2T  4096       // 73728 ushorts: conv2_w bf16 [t][n=cout128][c64]
#define W2OB 40960      // 18432 ushorts: offset2_w bf16 BT [n=32pad][k=576]
#define SC1  59392      //    64  bn1 scale
#define SH1  59456      //    64  bn1 shift (bias folded)
#define SC2  59520      //   128  bn2 scale
#define SH2  59648      //   128  bn2 shift (bias folded)
#define POOL 59776      //  4096  pooled sums (zeroed in prep)
#define XP   65536      // 524288  x as NHWC4 fp32 [b][hw][4] (ch3=0)
#define H1B  589824     // 8388608 ushorts: h1 bf16 NHWC [b][hw][64]
#define OFF2 4784128    // 2359296 pixel-major [b][hw][18]
// end 7143424 floats = 28.6 MiB
#define W2T_U   8192    // ushort offsets
#define W2OB_U  81920
#define H1B_U   1179648

typedef __attribute__((ext_vector_type(8))) short bhalf8;
typedef __attribute__((ext_vector_type(8))) unsigned short u16x8;
typedef __attribute__((ext_vector_type(4))) float f32x4;

#define BPAD 72    // def2 LDS k-stride (ushorts)
#define OPAD 584   // off2 LDS n-row stride (ushorts): 1168B -> 2-way (free)

struct Tap { int i00, i01, i10, i11; float w00, w01, w10, w11; };

__device__ __forceinline__ Tap make_tap(float py, float px) {
    float y0f = floorf(py), x0f = floorf(px);
    float wy = py - y0f, wx = px - x0f;
    bool by0 = (y0f >= 0.f)  && (y0f < 64.f);
    bool by1 = (y0f >= -1.f) && (y0f < 63.f);
    bool bx0 = (x0f >= 0.f)  && (x0f < 64.f);
    bool bx1 = (x0f >= -1.f) && (x0f < 63.f);
    int y0 = min(max((int)y0f, 0), 63);
    int y1 = min(max((int)y0f + 1, 0), 63);
    int x0 = min(max((int)x0f, 0), 63);
    int x1 = min(max((int)x0f + 1, 0), 63);
    Tap tp;
    tp.i00 = y0 * 64 + x0; tp.i01 = y0 * 64 + x1;
    tp.i10 = y1 * 64 + x0; tp.i11 = y1 * 64 + x1;
    tp.w00 = (by0 && bx0) ? (1.f - wy) * (1.f - wx) : 0.f;
    tp.w01 = (by0 && bx1) ? (1.f - wy) * wx         : 0.f;
    tp.w10 = (by1 && bx0) ? wy * (1.f - wx)         : 0.f;
    tp.w11 = (by1 && bx1) ? wy * wx                 : 0.f;
    return tp;
}

__device__ __forceinline__ ushort f2bf(float f) {
    union { float f; uint u; } a; a.f = f;
    uint u = a.u;
    return (ushort)((u + 0x7fffu + ((u >> 16) & 1u)) >> 16);   // RNE
}
__device__ __forceinline__ float bf2f(ushort u) {
    union { uint u; float f; } a; a.u = ((uint)u) << 16;
    return a.f;
}

// ---- prep: weight transposes + BN folding + pool zero + x NHWC4 pack ----
__global__ __launch_bounds__(256) void k_prep(
    const float* __restrict__ x,
    const float* __restrict__ o1w, const float* __restrict__ c1w,
    const float* __restrict__ o2w, const float* __restrict__ c2w,
    const float* __restrict__ c1b, const float* __restrict__ g1,
    const float* __restrict__ be1, const float* __restrict__ m1,
    const float* __restrict__ v1,
    const float* __restrict__ c2b, const float* __restrict__ g2,
    const float* __restrict__ be2, const float* __restrict__ m2,
    const float* __restrict__ v2,
    float* __restrict__ ws) {
    int tid = blockIdx.x * 256 + threadIdx.x;
    ushort* wsu = (ushort*)ws;
    if (tid < 648) {                          // W1OT [t*4+c][18]
        int co = tid % 18, tc = tid / 18, c = tc & 3, t = tc >> 2;
        ws[W1OT + tid] = (c < 3) ? o1w[(co * 3 + c) * 9 + t] : 0.f;
    } else if (tid < 2952) {                  // W1T [t*4+c][64]
        int i = tid - 648;
        int co = i & 63, tc = i >> 6, c = tc & 3, t = tc >> 2;
        ws[W1T + i] = (c < 3) ? c1w[(co * 3 + c) * 9 + t] : 0.f;
    } else if (tid < 76680) {                 // W2T bf16 [t][n][c]
        int i = tid - 2952;
        int c = i & 63, n = (i >> 6) & 127, t = i >> 13;
        wsu[W2T_U + i] = f2bf(c2w[(n * 64 + c) * 9 + t]);
    } else if (tid < 95112) {                 // W2OB bf16 [n=32pad][k=576]
        int i = tid - 76680;
        int n = i / 576, k = i - n * 576;
        int c = k & 63, t = k >> 6;
        float v = (n < 18) ? o2w[(n * 64 + c) * 9 + t] : 0.f;
        wsu[W2OB_U + i] = f2bf(v);
    } else if (tid < 95176) {
        int i = tid - 95112;
        float s = g1[i] * rsqrtf(v1[i] + EPS);
        ws[SC1 + i] = s;
        ws[SH1 + i] = (c1b[i] - m1[i]) * s + be1[i];
    } else if (tid < 95304) {
        int i = tid - 95176;
        float s = g2[i] * rsqrtf(v2[i] + EPS);
        ws[SC2 + i] = s;
        ws[SH2 + i] = (c2b[i] - m2[i]) * s + be2[i];
    } else if (tid < 99400) {
        ws[POOL + tid - 95304] = 0.f;
    } else if (tid < 230472) {                // XP pack: x NCHW -> NHWC4
        int i = tid - 99400;                  // = b*4096 + hw
        int b = i >> 12, hw = i & 4095;
        const float* xpp = x + (size_t)b * 3 * 4096 + hw;
        f32x4 o;
        o[0] = xpp[0]; o[1] = xpp[4096]; o[2] = xpp[8192]; o[3] = 0.f;
        *(f32x4*)(ws + XP + (size_t)i * 4) = o;
    }
}

// ---- fused offset-conv1 + deform conv1 (3->64) + BN + ReLU -> h1 bf16 NHWC ----
// (256,3): cap occupancy target so the allocator gets ~168 regs -> no scratch.
__global__ __launch_bounds__(256, 3) void k_def1(
    const float* __restrict__ o1b, float* __restrict__ ws) {
    __shared__ float wo[648];
    __shared__ float wt[2304];
    for (int i = threadIdx.x; i < 648; i += 256) wo[i] = ws[W1OT + i];
    for (int i = threadIdx.x; i < 2304; i += 256) wt[i] = ws[W1T + i];
    __syncthreads();
    int tid = blockIdx.x * 256 + threadIdx.x;
    int b = tid >> 12, hw = tid & 4095, h = hw >> 6, w = hw & 63;
    const float* xp = ws + XP + (size_t)b * 16384;   // [hw][4]
    // off1 conv in registers
    float off[18];
#pragma unroll
    for (int i = 0; i < 18; ++i) off[i] = o1b[i];
#pragma unroll
    for (int t = 0; t < 9; ++t) {
        int yy = h + t / 3 - 1, xx = w + t % 3 - 1;
        f32x4 pv = (f32x4)0.f;
        if (yy >= 0 && yy < 64 && xx >= 0 && xx < 64)
            pv = *(const f32x4*)(xp + (yy * 64 + xx) * 4);
#pragma unroll
        for (int c = 0; c < 3; ++c) {
            const float* wp = wo + (t * 4 + c) * 18;
#pragma unroll
            for (int co = 0; co < 18; ++co) off[co] += pv[c] * wp[co];
        }
    }
    // deformed bilinear gather (4-ch vector taps)
    f32x4 v[9];
#pragma unroll
    for (int t = 0; t < 9; ++t) {
        Tap tp = make_tap((float)(h + t / 3 - 1) + off[2 * t],
                          (float)(w + t % 3 - 1) + off[2 * t + 1]);
        f32x4 c00 = *(const f32x4*)(xp + tp.i00 * 4);
        f32x4 c01 = *(const f32x4*)(xp + tp.i01 * 4);
        f32x4 c10 = *(const f32x4*)(xp + tp.i10 * 4);
        f32x4 c11 = *(const f32x4*)(xp + tp.i11 * 4);
        v[t] = tp.w00 * c00 + tp.w01 * c01 + tp.w10 * c10 + tp.w11 * c11;
    }
    const float* sc = ws + SC1;
    const float* sh = ws + SH1;
    ushort* op = (ushort*)ws + H1B_U + (size_t)(b * 4096 + hw) * 64;
#pragma unroll
    for (int ch = 0; ch < 2; ++ch) {
        float acc[32];
#pragma unroll
        for (int i = 0; i < 32; ++i) acc[i] = 0.f;
#pragma unroll
        for (int t = 0; t < 9; ++t)
#pragma unroll
            for (int c = 0; c < 3; ++c) {
                float vk = v[t][c];
                const float* wp = wt + (t * 4 + c) * 64 + ch * 32;
#pragma unroll
                for (int co = 0; co < 32; ++co) acc[co] += vk * wp[co];
            }
        ushort ob[32];
#pragma unroll
        for (int i = 0; i < 32; ++i) {
            int co = ch * 32 + i;
            ob[i] = f2bf(fmaxf(acc[i] * sc[co] + sh[co], 0.f));
        }
#pragma unroll
        for (int i = 0; i < 4; ++i)
            *(uint4*)(op + ch * 32 + i * 8) = *(const uint4*)(ob + i * 8);
    }
}

// ---- offset conv2 as bf16 MFMA GEMM, B staged once in LDS -> off2 [b][hw][18] ----
__global__ __launch_bounds__(256, 4) void k_off2(
    const float* __restrict__ o2b, float* __restrict__ ws) {
    __shared__ ushort Bl[32 * OPAD];         // [n][k] padded
    int g = blockIdx.x;
    int b = (g & 7) * 4 + ((g >> 3) & 3);    // 4 images per XCD
    int row = g >> 5;
    int tid = threadIdx.x, lane = tid & 63, wv = tid >> 6;
    int r = lane & 15, q = lane >> 4;
    int hw0 = row * 64 + wv * 16;
    const ushort* hb = (const ushort*)ws + H1B_U + (size_t)b * 262144;
    const ushort* bt = (const ushort*)ws + W2OB_U;
    // stage B (32 x 576 bf16) once
    for (int i = tid; i < 2304; i += 256) {
        int n = i / 72, kk = (i - n * 72) * 8;
        *(uint4*)(Bl + n * OPAD + kk) = *(const uint4*)(bt + n * 576 + kk);
    }
    __syncthreads();
    f32x4 acc[2];
    acc[0] = (f32x4)0.f; acc[1] = (f32x4)0.f;
#pragma unroll
    for (int t = 0; t < 9; ++t) {
        int yy = row + t / 3 - 1;
        int xx = wv * 16 + r + t % 3 - 1;
        bool val = (yy >= 0 && yy < 64 && xx >= 0 && xx < 64);
        int yyc = min(max(yy, 0), 63), xxc = min(max(xx, 0), 63);
        const ushort* ap = hb + (size_t)(yyc * 64 + xxc) * 64 + q * 8;
#pragma unroll
        for (int ks = 0; ks < 2; ++ks) {
            bhalf8 af = val ? *(const bhalf8*)(ap + ks * 32) : (bhalf8)(short)0;
            int kk = t * 64 + ks * 32 + q * 8;
#pragma unroll
            for (int nt = 0; nt < 2; ++nt) {
                bhalf8 bf = *(const bhalf8*)(Bl + (nt * 16 + r) * OPAD + kk);
                acc[nt] = __builtin_amdgcn_mfma_f32_16x16x32_bf16(af, bf, acc[nt], 0, 0, 0);
            }
        }
    }
#pragma unroll
    for (int nt = 0; nt < 2; ++nt) {
        int n = nt * 16 + r;
        if (n < 18) {
            float bias = o2b[n];
#pragma unroll
            for (int rr = 0; rr < 4; ++rr) {
                int hw = hw0 + q * 4 + rr;
                ws[OFF2 + (size_t)(b * 4096 + hw) * 18 + n] = acc[nt][rr] + bias;
            }
        }
    }
}

// ---- deform conv2 (64->128) implicit-GEMM bf16 MFMA + BN + ReLU + pool ----
// Single-buffer LDS B, offsets preloaded, (256,5) occupancy experiment.
__global__ __launch_bounds__(256, 5) void k_def2(float* __restrict__ ws) {
    __shared__ ushort Blds[128 * BPAD];
    int g = blockIdx.x;
    int b = (g & 7) * 4 + ((g >> 3) & 3);
    int row = g >> 5;
    int tid = threadIdx.x, lane = tid & 63, wv = tid >> 6;
    int r = lane & 15, q = lane >> 4;
    int px = wv * 16 + r;
    const ushort* hb = (const ushort*)ws + H1B_U + (size_t)b * 262144;
    const float* o2 = ws + OFF2 + (size_t)b * 73728 + (size_t)(row * 64 + px) * 18;
    const ushort* wB = (const ushort*)ws + W2T_U;
    int bn = tid >> 1, bc = (tid & 1) * 32;

    // preload all 9 taps' offsets (independent dwordx2 loads, issued up front)
    float2 off[9];
#pragma unroll
    for (int t = 0; t < 9; ++t) off[t] = *(const float2*)(o2 + 2 * t);

    f32x4 acc[8];
#pragma unroll
    for (int j = 0; j < 8; ++j) acc[j] = (f32x4)0.f;

    for (int t = 0; t < 9; ++t) {
        Tap tp = make_tap((float)(row + t / 3 - 1) + off[t].x,
                          (float)(px + t % 3 - 1) + off[t].y);
        if (t) __syncthreads();             // previous tap's B readers done
        {
            const uint4* s4 = (const uint4*)(wB + (t * 128 + bn) * 64 + bc);
            uint4 p0 = s4[0], p1 = s4[1], p2 = s4[2], p3 = s4[3];
            ushort* dst = Blds + bn * BPAD + bc;
            *(uint4*)(dst)      = p0;
            *(uint4*)(dst + 8)  = p1;
            *(uint4*)(dst + 16) = p2;
            *(uint4*)(dst + 24) = p3;
        }
        __syncthreads();
#pragma unroll
        for (int ks = 0; ks < 2; ++ks) {
            int ko = ks * 32 + q * 8;       // this lane's 8 channels
            bhalf8 bf[8];
#pragma unroll
            for (int nt = 0; nt < 8; ++nt)
                bf[nt] = *(const bhalf8*)(Blds + (nt * 16 + r) * BPAD + ko);
            u16x8 g00 = *(const u16x8*)(hb + (size_t)tp.i00 * 64 + ko);
            u16x8 g01 = *(const u16x8*)(hb + (size_t)tp.i01 * 64 + ko);
            u16x8 g10 = *(const u16x8*)(hb + (size_t)tp.i10 * 64 + ko);
            u16x8 g11 = *(const u16x8*)(hb + (size_t)tp.i11 * 64 + ko);
            f32x4 lo = (f32x4)0.f, hi = (f32x4)0.f;
#pragma unroll
            for (int j = 0; j < 4; ++j) {
                lo[j] = tp.w00 * bf2f(g00[j]) + tp.w01 * bf2f(g01[j])
                      + tp.w10 * bf2f(g10[j]) + tp.w11 * bf2f(g11[j]);
                hi[j] = tp.w00 * bf2f(g00[j + 4]) + tp.w01 * bf2f(g01[j + 4])
                      + tp.w10 * bf2f(g10[j + 4]) + tp.w11 * bf2f(g11[j + 4]);
            }
            bhalf8 af;
#pragma unroll
            for (int j = 0; j < 4; ++j) {
                af[j]     = (short)f2bf(lo[j]);
                af[j + 4] = (short)f2bf(hi[j]);
            }
#pragma unroll
            for (int nt = 0; nt < 8; ++nt)
                acc[nt] = __builtin_amdgcn_mfma_f32_16x16x32_bf16(af, bf[nt], acc[nt], 0, 0, 0);
        }
    }
    // epilogue: BN + ReLU + pool (h2 never materialized)
    const float* sc = ws + SC2;
    const float* sh = ws + SH2;
    float* pool = ws + POOL;
#pragma unroll
    for (int nt = 0; nt < 8; ++nt) {
        int col = nt * 16 + r;
        float s0 = sc[col], s1 = sh[col];
        float s = 0.f;
#pragma unroll
        for (int rr = 0; rr < 4; ++rr)
            s += fmaxf(acc[nt][rr] * s0 + s1, 0.f);
        s += __shfl_xor(s, 16);
        s += __shfl_xor(s, 32);
        if (lane < 16) atomicAdd(&pool[b * 128 + col], s);
    }
}

// ---- fused fc1+relu+fc2 ----
__global__ __launch_bounds__(256) void k_fc(
    const float* __restrict__ w1, const float* __restrict__ b1,
    const float* __restrict__ w2, const float* __restrict__ b2,
    const float* __restrict__ ws, float* __restrict__ out) {
    int b = blockIdx.x, o = threadIdx.x;
    __shared__ float pl[128];
    __shared__ float hl[256];
    if (o < 128) pl[o] = ws[POOL + b * 128 + o] * (1.f / 4096.f);
    __syncthreads();
    float s = b1[o];
    const float* wp = w1 + o * 128;
#pragma unroll 8
    for (int c = 0; c < 128; ++c) s += pl[c] * wp[c];
    hl[o] = fmaxf(s, 0.f);
    __syncthreads();
    if (o < 200) {
        float s2 = b2[o];
        const float* wp2 = w2 + o * 256;
#pragma unroll 8
        for (int c = 0; c < 256; ++c) s2 += hl[c] * wp2[c];
        out[b * 200 + o] = s2;
    }
}

extern "C" void kernel_launch(void* const* d_in, const int* in_sizes, int n_in,
                              void* d_out, int out_size, void* d_ws, size_t ws_size,
                              hipStream_t stream) {
    const float* x   = (const float*)d_in[0];
    const float* o1w = (const float*)d_in[1];
    const float* o1b = (const float*)d_in[2];
    const float* c1w = (const float*)d_in[3];
    const float* c1b = (const float*)d_in[4];
    const float* g1  = (const float*)d_in[5];
    const float* be1 = (const float*)d_in[6];
    const float* m1  = (const float*)d_in[7];
    const float* v1  = (const float*)d_in[8];
    const float* o2w = (const float*)d_in[9];
    const float* o2b = (const float*)d_in[10];
    const float* c2w = (const float*)d_in[11];
    const float* c2b = (const float*)d_in[12];
    const float* g2  = (const float*)d_in[13];
    const float* be2 = (const float*)d_in[14];
    const float* m2  = (const float*)d_in[15];
    const float* v2  = (const float*)d_in[16];
    const float* f1w = (const float*)d_in[17];
    const float* f1b = (const float*)d_in[18];
    const float* f2w = (const float*)d_in[19];
    const float* f2b = (const float*)d_in[20];
    float* ws  = (float*)d_ws;
    float* out = (float*)d_out;

    k_prep<<<901, 256, 0, stream>>>(x, o1w, c1w, o2w, c2w,
                                    c1b, g1, be1, m1, v1,
                                    c2b, g2, be2, m2, v2, ws);
    k_def1<<<512, 256, 0, stream>>>(o1b, ws);
    k_off2<<<2048, 256, 0, stream>>>(o2b, ws);
    k_def2<<<2048, 256, 0, stream>>>(ws);
    k_fc<<<32, 256, 0, stream>>>(f1w, f1b, f2w, f2b, ws, out);
}

// Round 9
// 301.942 us; speedup vs baseline: 1.5848x; 1.0589x over previous
//
#include <hip/hip_runtime.h>

#define EPS 1e-5f

// ---- d_ws layout (float offsets unless noted) ----
#define W1OT 0          //   648  offset1_w [t*4+c][18] (c=3 zero-pad)
#define W1T  1024       //  2304  conv1_w   [t*4+c][64] (c=3 zero-pad)
#define W2T  4096       // 73728 ushorts: conv2_w bf16 [t][n=cout128][c64]
#define W2OB 40960      // 18432 ushorts: offset2_w bf16 BT [n=32pad][k=576]
#define SC1  59392      //    64  bn1 scale
#define SH1  59456      //    64  bn1 shift (bias folded)
#define SC2  59520      //   128  bn2 scale
#define SH2  59648      //   128  bn2 shift (bias folded)
#define POOL 59776      //  4096  pooled sums (zeroed in prep)
#define XP   65536      // 524288  x as NHWC4 fp32 [b][hw][4] (ch3=0)
#define H1B  589824     // 8388608 ushorts: h1 bf16 NHWC [b][hw][64]
// end 4784128 floats = 19.1 MiB
#define W2T_U   8192    // ushort offsets
#define W2OB_U  81920
#define H1B_U   1179648

typedef __attribute__((ext_vector_type(8))) short bhalf8;
typedef __attribute__((ext_vector_type(8))) unsigned short u16x8;
typedef __attribute__((ext_vector_type(4))) float f32x4;

#define BPAD 72    // def2 LDS k-stride (ushorts)
#define OPAD 584   // off2 LDS n-row stride (ushorts): 1168B -> 2-way (free)

struct Tap { int i00, i01, i10, i11; float w00, w01, w10, w11; };

__device__ __forceinline__ Tap make_tap(float py, float px) {
    float y0f = floorf(py), x0f = floorf(px);
    float wy = py - y0f, wx = px - x0f;
    bool by0 = (y0f >= 0.f)  && (y0f < 64.f);
    bool by1 = (y0f >= -1.f) && (y0f < 63.f);
    bool bx0 = (x0f >= 0.f)  && (x0f < 64.f);
    bool bx1 = (x0f >= -1.f) && (x0f < 63.f);
    int y0 = min(max((int)y0f, 0), 63);
    int y1 = min(max((int)y0f + 1, 0), 63);
    int x0 = min(max((int)x0f, 0), 63);
    int x1 = min(max((int)x0f + 1, 0), 63);
    Tap tp;
    tp.i00 = y0 * 64 + x0; tp.i01 = y0 * 64 + x1;
    tp.i10 = y1 * 64 + x0; tp.i11 = y1 * 64 + x1;
    tp.w00 = (by0 && bx0) ? (1.f - wy) * (1.f - wx) : 0.f;
    tp.w01 = (by0 && bx1) ? (1.f - wy) * wx         : 0.f;
    tp.w10 = (by1 && bx0) ? wy * (1.f - wx)         : 0.f;
    tp.w11 = (by1 && bx1) ? wy * wx                 : 0.f;
    return tp;
}

__device__ __forceinline__ ushort f2bf(float f) {
    union { float f; uint u; } a; a.f = f;
    uint u = a.u;
    return (ushort)((u + 0x7fffu + ((u >> 16) & 1u)) >> 16);   // RNE
}
__device__ __forceinline__ float bf2f(ushort u) {
    union { uint u; float f; } a; a.u = ((uint)u) << 16;
    return a.f;
}

// ---- prep: weight transposes + BN folding + pool zero + x NHWC4 pack ----
__global__ __launch_bounds__(256) void k_prep(
    const float* __restrict__ x,
    const float* __restrict__ o1w, const float* __restrict__ c1w,
    const float* __restrict__ o2w, const float* __restrict__ c2w,
    const float* __restrict__ c1b, const float* __restrict__ g1,
    const float* __restrict__ be1, const float* __restrict__ m1,
    const float* __restrict__ v1,
    const float* __restrict__ c2b, const float* __restrict__ g2,
    const float* __restrict__ be2, const float* __restrict__ m2,
    const float* __restrict__ v2,
    float* __restrict__ ws) {
    int tid = blockIdx.x * 256 + threadIdx.x;
    ushort* wsu = (ushort*)ws;
    if (tid < 648) {                          // W1OT [t*4+c][18]
        int co = tid % 18, tc = tid / 18, c = tc & 3, t = tc >> 2;
        ws[W1OT + tid] = (c < 3) ? o1w[(co * 3 + c) * 9 + t] : 0.f;
    } else if (tid < 2952) {                  // W1T [t*4+c][64]
        int i = tid - 648;
        int co = i & 63, tc = i >> 6, c = tc & 3, t = tc >> 2;
        ws[W1T + i] = (c < 3) ? c1w[(co * 3 + c) * 9 + t] : 0.f;
    } else if (tid < 76680) {                 // W2T bf16 [t][n][c]
        int i = tid - 2952;
        int c = i & 63, n = (i >> 6) & 127, t = i >> 13;
        wsu[W2T_U + i] = f2bf(c2w[(n * 64 + c) * 9 + t]);
    } else if (tid < 95112) {                 // W2OB bf16 [n=32pad][k=576]
        int i = tid - 76680;
        int n = i / 576, k = i - n * 576;
        int c = k & 63, t = k >> 6;
        float v = (n < 18) ? o2w[(n * 64 + c) * 9 + t] : 0.f;
        wsu[W2OB_U + i] = f2bf(v);
    } else if (tid < 95176) {
        int i = tid - 95112;
        float s = g1[i] * rsqrtf(v1[i] + EPS);
        ws[SC1 + i] = s;
        ws[SH1 + i] = (c1b[i] - m1[i]) * s + be1[i];
    } else if (tid < 95304) {
        int i = tid - 95176;
        float s = g2[i] * rsqrtf(v2[i] + EPS);
        ws[SC2 + i] = s;
        ws[SH2 + i] = (c2b[i] - m2[i]) * s + be2[i];
    } else if (tid < 99400) {
        ws[POOL + tid - 95304] = 0.f;
    } else if (tid < 230472) {                // XP pack: x NCHW -> NHWC4
        int i = tid - 99400;                  // = b*4096 + hw
        int b = i >> 12, hw = i & 4095;
        const float* xpp = x + (size_t)b * 3 * 4096 + hw;
        f32x4 o;
        o[0] = xpp[0]; o[1] = xpp[4096]; o[2] = xpp[8192]; o[3] = 0.f;
        *(f32x4*)(ws + XP + (size_t)i * 4) = o;
    }
}

// ---- fused offset-conv1 + deform conv1 (3->64) + BN + ReLU -> h1 bf16 NHWC ----
__global__ __launch_bounds__(256, 3) void k_def1(
    const float* __restrict__ o1b, float* __restrict__ ws) {
    __shared__ float wo[648];
    __shared__ float wt[2304];
    for (int i = threadIdx.x; i < 648; i += 256) wo[i] = ws[W1OT + i];
    for (int i = threadIdx.x; i < 2304; i += 256) wt[i] = ws[W1T + i];
    __syncthreads();
    int tid = blockIdx.x * 256 + threadIdx.x;
    int b = tid >> 12, hw = tid & 4095, h = hw >> 6, w = hw & 63;
    const float* xp = ws + XP + (size_t)b * 16384;   // [hw][4]
    float off[18];
#pragma unroll
    for (int i = 0; i < 18; ++i) off[i] = o1b[i];
#pragma unroll
    for (int t = 0; t < 9; ++t) {
        int yy = h + t / 3 - 1, xx = w + t % 3 - 1;
        f32x4 pv = (f32x4)0.f;
        if (yy >= 0 && yy < 64 && xx >= 0 && xx < 64)
            pv = *(const f32x4*)(xp + (yy * 64 + xx) * 4);
#pragma unroll
        for (int c = 0; c < 3; ++c) {
            const float* wp = wo + (t * 4 + c) * 18;
#pragma unroll
            for (int co = 0; co < 18; ++co) off[co] += pv[c] * wp[co];
        }
    }
    f32x4 v[9];
#pragma unroll
    for (int t = 0; t < 9; ++t) {
        Tap tp = make_tap((float)(h + t / 3 - 1) + off[2 * t],
                          (float)(w + t % 3 - 1) + off[2 * t + 1]);
        f32x4 c00 = *(const f32x4*)(xp + tp.i00 * 4);
        f32x4 c01 = *(const f32x4*)(xp + tp.i01 * 4);
        f32x4 c10 = *(const f32x4*)(xp + tp.i10 * 4);
        f32x4 c11 = *(const f32x4*)(xp + tp.i11 * 4);
        v[t] = tp.w00 * c00 + tp.w01 * c01 + tp.w10 * c10 + tp.w11 * c11;
    }
    const float* sc = ws + SC1;
    const float* sh = ws + SH1;
    ushort* op = (ushort*)ws + H1B_U + (size_t)(b * 4096 + hw) * 64;
#pragma unroll
    for (int ch = 0; ch < 2; ++ch) {
        float acc[32];
#pragma unroll
        for (int i = 0; i < 32; ++i) acc[i] = 0.f;
#pragma unroll
        for (int t = 0; t < 9; ++t)
#pragma unroll
            for (int c = 0; c < 3; ++c) {
                float vk = v[t][c];
                const float* wp = wt + (t * 4 + c) * 64 + ch * 32;
#pragma unroll
                for (int co = 0; co < 32; ++co) acc[co] += vk * wp[co];
            }
        ushort ob[32];
#pragma unroll
        for (int i = 0; i < 32; ++i) {
            int co = ch * 32 + i;
            ob[i] = f2bf(fmaxf(acc[i] * sc[co] + sh[co], 0.f));
        }
#pragma unroll
        for (int i = 0; i < 4; ++i)
            *(uint4*)(op + ch * 32 + i * 8) = *(const uint4*)(ob + i * 8);
    }
}

// ---- FUSED offset-conv2 + deform conv2 (64->128) + BN + ReLU + pool ----
// Phase 1: off2 GEMM (B_off in LDS) -> offsets to LDS offL[64][18].
// Phase 2: round-5 def2 structure, offsets read from LDS.
// LDS reuse: [Boff 37376B] then [offL 4608B | Bdef 18432B].
__global__ __launch_bounds__(256, 4) void k_def2(
    const float* __restrict__ o2b, float* __restrict__ ws) {
    __shared__ ushort smem[32 * OPAD];       // 18688 ushorts = 37376 B
    float* offL = (float*)smem;              // 64*18 floats = 2304 ushorts
    ushort* Bdef = smem + 2304;              // 128*BPAD = 9216 ushorts
    int g = blockIdx.x;
    int b = (g & 7) * 4 + ((g >> 3) & 3);    // 4 images per XCD
    int row = g >> 5;
    int tid = threadIdx.x, lane = tid & 63, wv = tid >> 6;
    int r = lane & 15, q = lane >> 4;
    int px = wv * 16 + r;
    const ushort* hb = (const ushort*)ws + H1B_U + (size_t)b * 262144;
    const ushort* wB = (const ushort*)ws + W2T_U;
    const ushort* bt = (const ushort*)ws + W2OB_U;

    // ---- phase 0: stage B_off (32 x 576 bf16) ----
    for (int i = tid; i < 2304; i += 256) {
        int n = i / 72, kk = (i - n * 72) * 8;
        *(uint4*)(smem + n * OPAD + kk) = *(const uint4*)(bt + n * 576 + kk);
    }
    __syncthreads();

    // ---- phase 1: off2 GEMM for this row's 64 px ----
    f32x4 acc2[2];
    acc2[0] = (f32x4)0.f; acc2[1] = (f32x4)0.f;
#pragma unroll
    for (int t = 0; t < 9; ++t) {
        int yy = row + t / 3 - 1;
        int xx = px + t % 3 - 1;
        bool val = (yy >= 0 && yy < 64 && xx >= 0 && xx < 64);
        int yyc = min(max(yy, 0), 63), xxc = min(max(xx, 0), 63);
        const ushort* ap = hb + (size_t)(yyc * 64 + xxc) * 64 + q * 8;
#pragma unroll
        for (int ks = 0; ks < 2; ++ks) {
            bhalf8 af = val ? *(const bhalf8*)(ap + ks * 32) : (bhalf8)(short)0;
            int kk = t * 64 + ks * 32 + q * 8;
#pragma unroll
            for (int nt = 0; nt < 2; ++nt) {
                bhalf8 bf = *(const bhalf8*)(smem + (nt * 16 + r) * OPAD + kk);
                acc2[nt] = __builtin_amdgcn_mfma_f32_16x16x32_bf16(af, bf, acc2[nt], 0, 0, 0);
            }
        }
    }
    __syncthreads();                          // all waves done reading B_off
    // write offsets to LDS (wave-local region, C-layout scatter)
#pragma unroll
    for (int nt = 0; nt < 2; ++nt) {
        int n = nt * 16 + r;
        if (n < 18) {
            float bias = o2b[n];
#pragma unroll
            for (int rr = 0; rr < 4; ++rr)
                offL[(wv * 16 + q * 4 + rr) * 18 + n] = acc2[nt][rr] + bias;
        }
    }
    __syncthreads();

    // ---- phase 2: deform conv2 implicit GEMM ----
    f32x4 acc[8];
#pragma unroll
    for (int j = 0; j < 8; ++j) acc[j] = (f32x4)0.f;
    int bn = tid >> 1, bc = (tid & 1) * 32;

    for (int t = 0; t < 9; ++t) {
        float oy = offL[px * 18 + 2 * t];
        float ox = offL[px * 18 + 2 * t + 1];
        Tap tp = make_tap((float)(row + t / 3 - 1) + oy,
                          (float)(px + t % 3 - 1) + ox);
        if (t) __syncthreads();              // previous tap's B readers done
        {
            const uint4* s4 = (const uint4*)(wB + (t * 128 + bn) * 64 + bc);
            uint4 p0 = s4[0], p1 = s4[1], p2 = s4[2], p3 = s4[3];
            ushort* dst = Bdef + bn * BPAD + bc;
            *(uint4*)(dst)      = p0;
            *(uint4*)(dst + 8)  = p1;
            *(uint4*)(dst + 16) = p2;
            *(uint4*)(dst + 24) = p3;
        }
        __syncthreads();
#pragma unroll
        for (int ks = 0; ks < 2; ++ks) {
            int ko = ks * 32 + q * 8;        // this lane's 8 channels
            bhalf8 bf[8];
#pragma unroll
            for (int nt = 0; nt < 8; ++nt)
                bf[nt] = *(const bhalf8*)(Bdef + (nt * 16 + r) * BPAD + ko);
            u16x8 g00 = *(const u16x8*)(hb + (size_t)tp.i00 * 64 + ko);
            u16x8 g01 = *(const u16x8*)(hb + (size_t)tp.i01 * 64 + ko);
            u16x8 g10 = *(const u16x8*)(hb + (size_t)tp.i10 * 64 + ko);
            u16x8 g11 = *(const u16x8*)(hb + (size_t)tp.i11 * 64 + ko);
            f32x4 lo = (f32x4)0.f, hi = (f32x4)0.f;
#pragma unroll
            for (int j = 0; j < 4; ++j) {
                lo[j] = tp.w00 * bf2f(g00[j]) + tp.w01 * bf2f(g01[j])
                      + tp.w10 * bf2f(g10[j]) + tp.w11 * bf2f(g11[j]);
                hi[j] = tp.w00 * bf2f(g00[j + 4]) + tp.w01 * bf2f(g01[j + 4])
                      + tp.w10 * bf2f(g10[j + 4]) + tp.w11 * bf2f(g11[j + 4]);
            }
            bhalf8 af;
#pragma unroll
            for (int j = 0; j < 4; ++j) {
                af[j]     = (short)f2bf(lo[j]);
                af[j + 4] = (short)f2bf(hi[j]);
            }
#pragma unroll
            for (int nt = 0; nt < 8; ++nt)
                acc[nt] = __builtin_amdgcn_mfma_f32_16x16x32_bf16(af, bf[nt], acc[nt], 0, 0, 0);
        }
    }
    // epilogue: BN + ReLU + pool (h2 never materialized)
    const float* sc = ws + SC2;
    const float* sh = ws + SH2;
    float* pool = ws + POOL;
#pragma unroll
    for (int nt = 0; nt < 8; ++nt) {
        int col = nt * 16 + r;
        float s0 = sc[col], s1 = sh[col];
        float s = 0.f;
#pragma unroll
        for (int rr = 0; rr < 4; ++rr)
            s += fmaxf(acc[nt][rr] * s0 + s1, 0.f);
        s += __shfl_xor(s, 16);
        s += __shfl_xor(s, 32);
        if (lane < 16) atomicAdd(&pool[b * 128 + col], s);
    }
}

// ---- fused fc1+relu+fc2 ----
__global__ __launch_bounds__(256) void k_fc(
    const float* __restrict__ w1, const float* __restrict__ b1,
    const float* __restrict__ w2, const float* __restrict__ b2,
    const float* __restrict__ ws, float* __restrict__ out) {
    int b = blockIdx.x, o = threadIdx.x;
    __shared__ float pl[128];
    __shared__ float hl[256];
    if (o < 128) pl[o] = ws[POOL + b * 128 + o] * (1.f / 4096.f);
    __syncthreads();
    float s = b1[o];
    const float* wp = w1 + o * 128;
#pragma unroll 8
    for (int c = 0; c < 128; ++c) s += pl[c] * wp[c];
    hl[o] = fmaxf(s, 0.f);
    __syncthreads();
    if (o < 200) {
        float s2 = b2[o];
        const float* wp2 = w2 + o * 256;
#pragma unroll 8
        for (int c = 0; c < 256; ++c) s2 += hl[c] * wp2[c];
        out[b * 200 + o] = s2;
    }
}

extern "C" void kernel_launch(void* const* d_in, const int* in_sizes, int n_in,
                              void* d_out, int out_size, void* d_ws, size_t ws_size,
                              hipStream_t stream) {
    const float* x   = (const float*)d_in[0];
    const float* o1w = (const float*)d_in[1];
    const float* o1b = (const float*)d_in[2];
    const float* c1w = (const float*)d_in[3];
    const float* c1b = (const float*)d_in[4];
    const float* g1  = (const float*)d_in[5];
    const float* be1 = (const float*)d_in[6];
    const float* m1  = (const float*)d_in[7];
    const float* v1  = (const float*)d_in[8];
    const float* o2w = (const float*)d_in[9];
    const float* o2b = (const float*)d_in[10];
    const float* c2w = (const float*)d_in[11];
    const float* c2b = (const float*)d_in[12];
    const float* g2  = (const float*)d_in[13];
    const float* be2 = (const float*)d_in[14];
    const float* m2  = (const float*)d_in[15];
    const float* v2  = (const float*)d_in[16];
    const float* f1w = (const float*)d_in[17];
    const float* f1b = (const float*)d_in[18];
    const float* f2w = (const float*)d_in[19];
    const float* f2b = (const float*)d_in[20];
    float* ws  = (float*)d_ws;
    float* out = (float*)d_out;

    k_prep<<<901, 256, 0, stream>>>(x, o1w, c1w, o2w, c2w,
                                    c1b, g1, be1, m1, v1,
                                    c2b, g2, be2, m2, v2, ws);
    k_def1<<<512, 256, 0, stream>>>(o1b, ws);
    k_def2<<<2048, 256, 0, stream>>>(o2b, ws);
    k_fc<<<32, 256, 0, stream>>>(f1w, f1b, f2w, f2b, ws, out);
}

// Round 10
// 290.224 us; speedup vs baseline: 1.6488x; 1.0404x over previous
//
#include <hip/hip_runtime.h>

#define EPS 1e-5f

// ---- d_ws layout (float offsets unless noted) ----
#define W1OT 0          //   648  offset1_w [t*4+c][18] (c=3 zero-pad)
#define W1B  1024       //  2048 ushorts: conv1_w bf16 [n=64][k=32] (k=t*3+c, 27..31 zero)
#define W2T  4096       // 73728 ushorts: conv2_w bf16 [t][n=cout128][c64]
#define W2OB 40960      // 18432 ushorts: offset2_w bf16 BT [n=32pad][k=576]
#define SC1  59392      //    64  bn1 scale
#define SH1  59456      //    64  bn1 shift (bias folded)
#define SC2  59520      //   128  bn2 scale
#define SH2  59648      //   128  bn2 shift (bias folded)
#define POOL 59776      //  4096  pooled sums (zeroed in prep)
#define XP   65536      // 524288  x as NHWC4 fp32 [b][hw][4] (ch3=0)
#define H1B  589824     // 8388608 ushorts: h1 bf16 NHWC [b][hw][64]
// end 4784128 floats = 19.1 MiB
#define W1B_U   2048    // ushort offsets
#define W2T_U   8192
#define W2OB_U  81920
#define H1B_U   1179648

typedef __attribute__((ext_vector_type(8))) short bhalf8;
typedef __attribute__((ext_vector_type(8))) unsigned short u16x8;
typedef __attribute__((ext_vector_type(4))) float f32x4;

#define BPAD 72    // def2 LDS k-stride (ushorts)
#define OPAD 584   // off2 LDS n-row stride (ushorts)
#define APAD 40    // def1 LDS k-row stride (ushorts): 80B, 16B-aligned, <=2-way

struct Tap { int i00, i01, i10, i11; float w00, w01, w10, w11; };

__device__ __forceinline__ Tap make_tap(float py, float px) {
    float y0f = floorf(py), x0f = floorf(px);
    float wy = py - y0f, wx = px - x0f;
    bool by0 = (y0f >= 0.f)  && (y0f < 64.f);
    bool by1 = (y0f >= -1.f) && (y0f < 63.f);
    bool bx0 = (x0f >= 0.f)  && (x0f < 64.f);
    bool bx1 = (x0f >= -1.f) && (x0f < 63.f);
    int y0 = min(max((int)y0f, 0), 63);
    int y1 = min(max((int)y0f + 1, 0), 63);
    int x0 = min(max((int)x0f, 0), 63);
    int x1 = min(max((int)x0f + 1, 0), 63);
    Tap tp;
    tp.i00 = y0 * 64 + x0; tp.i01 = y0 * 64 + x1;
    tp.i10 = y1 * 64 + x0; tp.i11 = y1 * 64 + x1;
    tp.w00 = (by0 && bx0) ? (1.f - wy) * (1.f - wx) : 0.f;
    tp.w01 = (by0 && bx1) ? (1.f - wy) * wx         : 0.f;
    tp.w10 = (by1 && bx0) ? wy * (1.f - wx)         : 0.f;
    tp.w11 = (by1 && bx1) ? wy * wx                 : 0.f;
    return tp;
}

__device__ __forceinline__ ushort f2bf(float f) {
    union { float f; uint u; } a; a.f = f;
    uint u = a.u;
    return (ushort)((u + 0x7fffu + ((u >> 16) & 1u)) >> 16);   // RNE
}
__device__ __forceinline__ float bf2f(ushort u) {
    union { uint u; float f; } a; a.u = ((uint)u) << 16;
    return a.f;
}

// ---- prep: weight transposes + BN folding + pool zero + x NHWC4 pack ----
__global__ __launch_bounds__(256) void k_prep(
    const float* __restrict__ x,
    const float* __restrict__ o1w, const float* __restrict__ c1w,
    const float* __restrict__ o2w, const float* __restrict__ c2w,
    const float* __restrict__ c1b, const float* __restrict__ g1,
    const float* __restrict__ be1, const float* __restrict__ m1,
    const float* __restrict__ v1,
    const float* __restrict__ c2b, const float* __restrict__ g2,
    const float* __restrict__ be2, const float* __restrict__ m2,
    const float* __restrict__ v2,
    float* __restrict__ ws) {
    int tid = blockIdx.x * 256 + threadIdx.x;
    ushort* wsu = (ushort*)ws;
    if (tid < 648) {                          // W1OT [t*4+c][18]
        int co = tid % 18, tc = tid / 18, c = tc & 3, t = tc >> 2;
        ws[W1OT + tid] = (c < 3) ? o1w[(co * 3 + c) * 9 + t] : 0.f;
    } else if (tid < 2696) {                  // W1B bf16 [n][k=32], k=t*3+c
        int i = tid - 648;
        int n = i >> 5, k = i & 31;
        float v = 0.f;
        if (k < 27) { int c = k % 3, t = k / 3; v = c1w[(n * 3 + c) * 9 + t]; }
        wsu[W1B_U + i] = f2bf(v);
    } else if (tid < 76424) {                 // W2T bf16 [t][n][c]
        int i = tid - 2696;
        int c = i & 63, n = (i >> 6) & 127, t = i >> 13;
        wsu[W2T_U + i] = f2bf(c2w[(n * 64 + c) * 9 + t]);
    } else if (tid < 94856) {                 // W2OB bf16 [n=32pad][k=576]
        int i = tid - 76424;
        int n = i / 576, k = i - n * 576;
        int c = k & 63, t = k >> 6;
        float v = (n < 18) ? o2w[(n * 64 + c) * 9 + t] : 0.f;
        wsu[W2OB_U + i] = f2bf(v);
    } else if (tid < 94920) {
        int i = tid - 94856;
        float s = g1[i] * rsqrtf(v1[i] + EPS);
        ws[SC1 + i] = s;
        ws[SH1 + i] = (c1b[i] - m1[i]) * s + be1[i];
    } else if (tid < 95048) {
        int i = tid - 94920;
        float s = g2[i] * rsqrtf(v2[i] + EPS);
        ws[SC2 + i] = s;
        ws[SH2 + i] = (c2b[i] - m2[i]) * s + be2[i];
    } else if (tid < 99144) {
        ws[POOL + tid - 95048] = 0.f;
    } else if (tid < 230216) {                // XP pack: x NCHW -> NHWC4
        int i = tid - 99144;                  // = b*4096 + hw
        int b = i >> 12, hw = i & 4095;
        const float* xpp = x + (size_t)b * 3 * 4096 + hw;
        f32x4 o;
        o[0] = xpp[0]; o[1] = xpp[4096]; o[2] = xpp[8192]; o[3] = 0.f;
        *(f32x4*)(ws + XP + (size_t)i * 4) = o;
    }
}

// ---- fused offset-conv1 + deform conv1 (3->64) as MFMA implicit GEMM ----
// WG = 4 rows (256 px). Phase A: per-thread off1 conv + gathers -> A-LDS bf16
// [px][k=32] (k=t*3+c, zero-padded). Phase B: K=32 -> one MFMA per tile;
// wave = 4 m-tiles x 4 n-tiles. Epilogue BN+ReLU -> h1 bf16 NHWC.
__global__ __launch_bounds__(256, 4) void k_def1(
    const float* __restrict__ o1b, float* __restrict__ ws) {
    __shared__ ushort Alds[256 * APAD];       // 20 KB
    __shared__ ushort Blds[64 * APAD];        // 5 KB
    __shared__ float wo[648];
    __shared__ float scl[128];
    int tid = threadIdx.x;
    for (int i = tid; i < 648; i += 256) wo[i] = ws[W1OT + i];
    if (tid < 128) scl[tid] = ws[SC1 + tid];  // SC1[0..63], SH1 at +64
    {   // stage B: 64 rows x 32 ushorts -> padded rows
        const ushort* src = (const ushort*)ws + W1B_U;
        if (tid < 128) {
            int n = tid >> 1, half = (tid & 1) * 16;
            *(uint4*)(Blds + n * APAD + half)     = *(const uint4*)(src + n * 32 + half);
            *(uint4*)(Blds + n * APAD + half + 8) = *(const uint4*)(src + n * 32 + half + 8);
        }
    }
    int g = blockIdx.x;
    int b = (g & 7) * 4 + ((g >> 3) & 3);     // XCD swizzle: 4 images/XCD
    int row0 = (g >> 5) * 4;
    int h = row0 + (tid >> 6), w = tid & 63;
    const float* xp = ws + XP + (size_t)b * 16384;

    // ---- phase A: off1 conv ----
    float off[18];
#pragma unroll
    for (int i = 0; i < 18; ++i) off[i] = o1b[i];
    __syncthreads();                          // wo staged
#pragma unroll
    for (int t = 0; t < 9; ++t) {
        int yy = h + t / 3 - 1, xx = w + t % 3 - 1;
        f32x4 pv = (f32x4)0.f;
        if (yy >= 0 && yy < 64 && xx >= 0 && xx < 64)
            pv = *(const f32x4*)(xp + (yy * 64 + xx) * 4);
#pragma unroll
        for (int c = 0; c < 3; ++c) {
            const float* wp = wo + (t * 4 + c) * 18;
#pragma unroll
            for (int co = 0; co < 18; ++co) off[co] += pv[c] * wp[co];
        }
    }
    // gathers -> bf16 k-row
    ushort ob[32];
#pragma unroll
    for (int i = 0; i < 32; ++i) ob[i] = 0;
#pragma unroll
    for (int t = 0; t < 9; ++t) {
        Tap tp = make_tap((float)(h + t / 3 - 1) + off[2 * t],
                          (float)(w + t % 3 - 1) + off[2 * t + 1]);
        f32x4 c00 = *(const f32x4*)(xp + tp.i00 * 4);
        f32x4 c01 = *(const f32x4*)(xp + tp.i01 * 4);
        f32x4 c10 = *(const f32x4*)(xp + tp.i10 * 4);
        f32x4 c11 = *(const f32x4*)(xp + tp.i11 * 4);
        f32x4 vt = tp.w00 * c00 + tp.w01 * c01 + tp.w10 * c10 + tp.w11 * c11;
        ob[t * 3 + 0] = f2bf(vt[0]);
        ob[t * 3 + 1] = f2bf(vt[1]);
        ob[t * 3 + 2] = f2bf(vt[2]);
    }
    {
        ushort* ar = Alds + tid * APAD;
#pragma unroll
        for (int i = 0; i < 4; ++i)
            *(uint4*)(ar + i * 8) = *(const uint4*)(ob + i * 8);
    }
    __syncthreads();

    // ---- phase B: MFMA, wave = px[wv*64 .. +64) x all 64 couts ----
    int lane = tid & 63, wv = tid >> 6;
    int r = lane & 15, q = lane >> 4;
    bhalf8 bf[4];
#pragma unroll
    for (int nt = 0; nt < 4; ++nt)
        bf[nt] = *(const bhalf8*)(Blds + (nt * 16 + r) * APAD + q * 8);
    f32x4 acc[4][4];
#pragma unroll
    for (int mt = 0; mt < 4; ++mt) {
        bhalf8 af = *(const bhalf8*)(Alds + (wv * 64 + mt * 16 + r) * APAD + q * 8);
#pragma unroll
        for (int nt = 0; nt < 4; ++nt)
            acc[mt][nt] = __builtin_amdgcn_mfma_f32_16x16x32_bf16(af, bf[nt], (f32x4)0.f, 0, 0, 0);
    }
    // ---- epilogue: BN + ReLU -> h1 bf16 ----
    ushort* hb = (ushort*)ws + H1B_U + (size_t)(b * 4096 + row0 * 64) * 64;
#pragma unroll
    for (int nt = 0; nt < 4; ++nt) {
        int col = nt * 16 + r;
        float s0 = scl[col], s1 = scl[64 + col];
#pragma unroll
        for (int mt = 0; mt < 4; ++mt) {
            int pxl = wv * 64 + mt * 16 + q * 4;
#pragma unroll
            for (int rr = 0; rr < 4; ++rr)
                hb[(size_t)(pxl + rr) * 64 + col] =
                    f2bf(fmaxf(acc[mt][nt][rr] * s0 + s1, 0.f));
        }
    }
}

// ---- FUSED offset-conv2 + deform conv2 (64->128) + BN + ReLU + pool ----
__global__ __launch_bounds__(256, 4) void k_def2(
    const float* __restrict__ o2b, float* __restrict__ ws) {
    __shared__ ushort smem[32 * OPAD];       // 18688 ushorts = 37376 B
    float* offL = (float*)smem;              // 64*18 floats = 2304 ushorts
    ushort* Bdef = smem + 2304;              // 128*BPAD = 9216 ushorts
    int g = blockIdx.x;
    int b = (g & 7) * 4 + ((g >> 3) & 3);    // 4 images per XCD
    int row = g >> 5;
    int tid = threadIdx.x, lane = tid & 63, wv = tid >> 6;
    int r = lane & 15, q = lane >> 4;
    int px = wv * 16 + r;
    const ushort* hb = (const ushort*)ws + H1B_U + (size_t)b * 262144;
    const ushort* wB = (const ushort*)ws + W2T_U;
    const ushort* bt = (const ushort*)ws + W2OB_U;

    // ---- phase 0: stage B_off (32 x 576 bf16) ----
    for (int i = tid; i < 2304; i += 256) {
        int n = i / 72, kk = (i - n * 72) * 8;
        *(uint4*)(smem + n * OPAD + kk) = *(const uint4*)(bt + n * 576 + kk);
    }
    __syncthreads();

    // ---- phase 1: off2 GEMM for this row's 64 px ----
    f32x4 acc2[2];
    acc2[0] = (f32x4)0.f; acc2[1] = (f32x4)0.f;
#pragma unroll
    for (int t = 0; t < 9; ++t) {
        int yy = row + t / 3 - 1;
        int xx = px + t % 3 - 1;
        bool val = (yy >= 0 && yy < 64 && xx >= 0 && xx < 64);
        int yyc = min(max(yy, 0), 63), xxc = min(max(xx, 0), 63);
        const ushort* ap = hb + (size_t)(yyc * 64 + xxc) * 64 + q * 8;
#pragma unroll
        for (int ks = 0; ks < 2; ++ks) {
            bhalf8 af = val ? *(const bhalf8*)(ap + ks * 32) : (bhalf8)(short)0;
            int kk = t * 64 + ks * 32 + q * 8;
#pragma unroll
            for (int nt = 0; nt < 2; ++nt) {
                bhalf8 bf = *(const bhalf8*)(smem + (nt * 16 + r) * OPAD + kk);
                acc2[nt] = __builtin_amdgcn_mfma_f32_16x16x32_bf16(af, bf, acc2[nt], 0, 0, 0);
            }
        }
    }
    __syncthreads();                          // all waves done reading B_off
#pragma unroll
    for (int nt = 0; nt < 2; ++nt) {
        int n = nt * 16 + r;
        if (n < 18) {
            float bias = o2b[n];
#pragma unroll
            for (int rr = 0; rr < 4; ++rr)
                offL[(wv * 16 + q * 4 + rr) * 18 + n] = acc2[nt][rr] + bias;
        }
    }
    __syncthreads();

    // ---- phase 2: deform conv2 implicit GEMM ----
    f32x4 acc[8];
#pragma unroll
    for (int j = 0; j < 8; ++j) acc[j] = (f32x4)0.f;
    int bn = tid >> 1, bc = (tid & 1) * 32;

    for (int t = 0; t < 9; ++t) {
        float oy = offL[px * 18 + 2 * t];
        float ox = offL[px * 18 + 2 * t + 1];
        Tap tp = make_tap((float)(row + t / 3 - 1) + oy,
                          (float)(px + t % 3 - 1) + ox);
        if (t) __syncthreads();
        {
            const uint4* s4 = (const uint4*)(wB + (t * 128 + bn) * 64 + bc);
            uint4 p0 = s4[0], p1 = s4[1], p2 = s4[2], p3 = s4[3];
            ushort* dst = Bdef + bn * BPAD + bc;
            *(uint4*)(dst)      = p0;
            *(uint4*)(dst + 8)  = p1;
            *(uint4*)(dst + 16) = p2;
            *(uint4*)(dst + 24) = p3;
        }
        __syncthreads();
#pragma unroll
        for (int ks = 0; ks < 2; ++ks) {
            int ko = ks * 32 + q * 8;
            bhalf8 bf[8];
#pragma unroll
            for (int nt = 0; nt < 8; ++nt)
                bf[nt] = *(const bhalf8*)(Bdef + (nt * 16 + r) * BPAD + ko);
            u16x8 g00 = *(const u16x8*)(hb + (size_t)tp.i00 * 64 + ko);
            u16x8 g01 = *(const u16x8*)(hb + (size_t)tp.i01 * 64 + ko);
            u16x8 g10 = *(const u16x8*)(hb + (size_t)tp.i10 * 64 + ko);
            u16x8 g11 = *(const u16x8*)(hb + (size_t)tp.i11 * 64 + ko);
            f32x4 lo = (f32x4)0.f, hi = (f32x4)0.f;
#pragma unroll
            for (int j = 0; j < 4; ++j) {
                lo[j] = tp.w00 * bf2f(g00[j]) + tp.w01 * bf2f(g01[j])
                      + tp.w10 * bf2f(g10[j]) + tp.w11 * bf2f(g11[j]);
                hi[j] = tp.w00 * bf2f(g00[j + 4]) + tp.w01 * bf2f(g01[j + 4])
                      + tp.w10 * bf2f(g10[j + 4]) + tp.w11 * bf2f(g11[j + 4]);
            }
            bhalf8 af;
#pragma unroll
            for (int j = 0; j < 4; ++j) {
                af[j]     = (short)f2bf(lo[j]);
                af[j + 4] = (short)f2bf(hi[j]);
            }
#pragma unroll
            for (int nt = 0; nt < 8; ++nt)
                acc[nt] = __builtin_amdgcn_mfma_f32_16x16x32_bf16(af, bf[nt], acc[nt], 0, 0, 0);
        }
    }
    // epilogue: BN + ReLU + pool (h2 never materialized)
    const float* sc = ws + SC2;
    const float* sh = ws + SH2;
    float* pool = ws + POOL;
#pragma unroll
    for (int nt = 0; nt < 8; ++nt) {
        int col = nt * 16 + r;
        float s0 = sc[col], s1 = sh[col];
        float s = 0.f;
#pragma unroll
        for (int rr = 0; rr < 4; ++rr)
            s += fmaxf(acc[nt][rr] * s0 + s1, 0.f);
        s += __shfl_xor(s, 16);
        s += __shfl_xor(s, 32);
        if (lane < 16) atomicAdd(&pool[b * 128 + col], s);
    }
}

// ---- fused fc1+relu+fc2 ----
__global__ __launch_bounds__(256) void k_fc(
    const float* __restrict__ w1, const float* __restrict__ b1,
    const float* __restrict__ w2, const float* __restrict__ b2,
    const float* __restrict__ ws, float* __restrict__ out) {
    int b = blockIdx.x, o = threadIdx.x;
    __shared__ float pl[128];
    __shared__ float hl[256];
    if (o < 128) pl[o] = ws[POOL + b * 128 + o] * (1.f / 4096.f);
    __syncthreads();
    float s = b1[o];
    const float* wp = w1 + o * 128;
#pragma unroll 8
    for (int c = 0; c < 128; ++c) s += pl[c] * wp[c];
    hl[o] = fmaxf(s, 0.f);
    __syncthreads();
    if (o < 200) {
        float s2 = b2[o];
        const float* wp2 = w2 + o * 256;
#pragma unroll 8
        for (int c = 0; c < 256; ++c) s2 += hl[c] * wp2[c];
        out[b * 200 + o] = s2;
    }
}

extern "C" void kernel_launch(void* const* d_in, const int* in_sizes, int n_in,
                              void* d_out, int out_size, void* d_ws, size_t ws_size,
                              hipStream_t stream) {
    const float* x   = (const float*)d_in[0];
    const float* o1w = (const float*)d_in[1];
    const float* o1b = (const float*)d_in[2];
    const float* c1w = (const float*)d_in[3];
    const float* c1b = (const float*)d_in[4];
    const float* g1  = (const float*)d_in[5];
    const float* be1 = (const float*)d_in[6];
    const float* m1  = (const float*)d_in[7];
    const float* v1  = (const float*)d_in[8];
    const float* o2w = (const float*)d_in[9];
    const float* o2b = (const float*)d_in[10];
    const float* c2w = (const float*)d_in[11];
    const float* c2b = (const float*)d_in[12];
    const float* g2  = (const float*)d_in[13];
    const float* be2 = (const float*)d_in[14];
    const float* m2  = (const float*)d_in[15];
    const float* v2  = (const float*)d_in[16];
    const float* f1w = (const float*)d_in[17];
    const float* f1b = (const float*)d_in[18];
    const float* f2w = (const float*)d_in[19];
    const float* f2b = (const float*)d_in[20];
    float* ws  = (float*)d_ws;
    float* out = (float*)d_out;

    k_prep<<<900, 256, 0, stream>>>(x, o1w, c1w, o2w, c2w,
                                    c1b, g1, be1, m1, v1,
                                    c2b, g2, be2, m2, v2, ws);
    k_def1<<<512, 256, 0, stream>>>(o1b, ws);
    k_def2<<<2048, 256, 0, stream>>>(o2b, ws);
    k_fc<<<32, 256, 0, stream>>>(f1w, f1b, f2w, f2b, ws, out);
}